// Round 11
// baseline (1360.012 us; speedup 1.0000x reference)
//
#include <hip/hip_runtime.h>
#include <hip/hip_fp8.h>

#define NN 1048576   // nodes (= 2^20, src fits 20 bits)
#define NE 8388608   // edges
#define NG 32768     // graphs
#define DD 9         // emb dim
#define HH 18        // hidden
#define BN_EPS 1e-5f

#define NPB 512      // nodes per dst bucket
#define NB  2048     // dst buckets
#define P1B 512      // k_p1 / counthist blocks
#define P3MAX 5120   // max edges per bucket staged in k_p3 (Poisson(4096), safe)
#define P3KEYS 2048  // 512 nodes x 4 src-quartiles
#define VNB 128      // k_vn blocks (<= CU count -> co-resident, spin barrier safe)

// spread stats: 64 copies x 64 chans. within-copy offsets:
#define NSUM1 0      // 18
#define NSQ1  18     // 18
#define NSUM2 36     // 9
#define NSQ2  45     // 9
#define OUTS  54     // 9
#define VBASE 4096   // VN stats (single copy)
#define VSUM1 (VBASE+0)
#define VSQ1  (VBASE+18)
#define VSUM2 (VBASE+36)
#define VSQ2  (VBASE+45)
#define BARS  4160   // 4 ints: {cnt0,gen0,cnt1,gen1}, zeroed by stats memset
#define STATS_FLOATS 4224

typedef float fv4 __attribute__((ext_vector_type(4)));
typedef unsigned uv4 __attribute__((ext_vector_type(4)));

__device__ __forceinline__ float waveReduce(float v) {
#pragma unroll
  for (int off = 32; off > 0; off >>= 1) v += __shfl_down(v, off, 64);
  return v;
}
__device__ __forceinline__ unsigned f8enc(float f) {
  __hip_fp8_e4m3 v(f);
  return (unsigned)v.__x;
}
__device__ __forceinline__ float f8dec(unsigned b) {
  __hip_fp8_e4m3 v;
  v.__x = (__hip_fp8_storage_t)b;
  return (float)v;
}
// bf16 round-to-nearest-even pack/unpack
__device__ __forceinline__ unsigned bf16r(float x) {
  unsigned u = __float_as_uint(x);
  unsigned r = u + 0x7FFFu + ((u >> 16) & 1u);
  return r >> 16;
}
__device__ __forceinline__ unsigned pk2(float a, float b) {
  return bf16r(a) | (bf16r(b) << 16);
}
__device__ __forceinline__ float lo16(unsigned u) { return __uint_as_float(u << 16); }
__device__ __forceinline__ float hi16(unsigned u) { return __uint_as_float(u & 0xFFFF0000u); }

__device__ __forceinline__ void pack9(uv4* __restrict__ b8, unsigned short* __restrict__ b1,
                                      size_t n, const float* v) {
  uv4 p;
  p.x = pk2(v[0], v[1]); p.y = pk2(v[2], v[3]);
  p.z = pk2(v[4], v[5]); p.w = pk2(v[6], v[7]);
  __builtin_nontemporal_store(p, &b8[n]);
  __builtin_nontemporal_store((unsigned short)bf16r(v[8]), &b1[n]);
}
__device__ __forceinline__ void unpack9(const uv4* __restrict__ b8,
                                        const unsigned short* __restrict__ b1,
                                        size_t n, float* v) {
  uv4 P = __builtin_nontemporal_load(&b8[n]);
  unsigned short s = b1[n];
  v[0] = lo16(P.x); v[1] = hi16(P.x); v[2] = lo16(P.y); v[3] = hi16(P.y);
  v[4] = lo16(P.z); v[5] = hi16(P.z); v[6] = lo16(P.w); v[7] = hi16(P.w);
  v[8] = __uint_as_float((unsigned)s << 16);
}

// ---------------- binning (once per launch) ----------------
// SINGLE-PASS deterministic counting-sort (no coarse intermediate, no k_p2):
// counthist -> per-(block,bucket) counts; scan + scanB -> per-(block,bucket)
// write bases; p1 scatters FINAL 32-bit records straight into fine buckets;
// p3 sorts each bucket by (local_dst, src_quartile) and emits CSR + rpo.

__global__ void __launch_bounds__(1024)
k_counthist(const int* __restrict__ ei, int* __restrict__ cnt_pad,
            int* __restrict__ blkcnt) {
  __shared__ int hist[NB];   // 8 KB
  int tid = threadIdx.x;
  for (int i = tid; i < NB; i += 1024) hist[i] = 0;
  __syncthreads();
  const int CH = NE / P1B;   // 16384
  int base = blockIdx.x * CH;
  for (int i = tid; i < CH; i += 1024)
    atomicAdd(&hist[ei[NE + base + i] >> 9], 1);
  __syncthreads();
  for (int i = tid; i < NB; i += 1024) {
    int h = hist[i];
    blkcnt[(size_t)blockIdx.x * NB + i] = h;
    if (h) atomicAdd(&cnt_pad[i * 16], h);
  }
}

__global__ void k_scan(const int* __restrict__ cnt_pad, int* __restrict__ bucket_base) {
  __shared__ int tsum[256];
  int tid = threadIdx.x;
  int c[8];
  int run = 0;
#pragma unroll
  for (int k = 0; k < 8; ++k) { c[k] = cnt_pad[(tid * 8 + k) * 16]; run += c[k]; }
  tsum[tid] = run;
  __syncthreads();
  for (int off = 1; off < 256; off <<= 1) {
    int v = (tid >= off) ? tsum[tid - off] : 0;
    __syncthreads();
    tsum[tid] += v;
    __syncthreads();
  }
  int excl = tsum[tid] - run;
#pragma unroll
  for (int k = 0; k < 8; ++k) {
    bucket_base[tid * 8 + k] = excl;
    excl += c[k];
  }
  if (tid == 255) bucket_base[NB] = tsum[255];
}

// per-bucket exclusive scan over the P1B block counts -> write bases (in place)
__global__ void k_scanB(int* __restrict__ blkcnt, const int* __restrict__ bucket_base) {
  __shared__ int tsum[256];
  int tid = threadIdx.x;
  int b = blockIdx.x;
  int c0 = blkcnt[(size_t)(2 * tid) * NB + b];
  int c1 = blkcnt[(size_t)(2 * tid + 1) * NB + b];
  int run = c0 + c1;
  tsum[tid] = run;
  __syncthreads();
  for (int off = 1; off < 256; off <<= 1) {
    int v = (tid >= off) ? tsum[tid - off] : 0;
    __syncthreads();
    tsum[tid] += v;
    __syncthreads();
  }
  int excl = tsum[tid] - run + bucket_base[b];
  blkcnt[(size_t)(2 * tid) * NB + b] = excl;
  blkcnt[(size_t)(2 * tid + 1) * NB + b] = excl + c0;
}

// scatter final records (src | local_dst<<20 | attr<<29) at precomputed bases
__global__ void __launch_bounds__(1024)
k_p1(const int* __restrict__ ei, const int* __restrict__ ea,
     const int* __restrict__ blkcnt, unsigned* __restrict__ binned) {
  __shared__ int lcnt[NB];    // 8 KB
  __shared__ int lbase[NB];   // 8 KB
  int tid = threadIdx.x;
  for (int i = tid; i < NB; i += 1024) {
    lcnt[i] = 0;
    lbase[i] = blkcnt[(size_t)blockIdx.x * NB + i];
  }
  __syncthreads();
  const int CH = NE / P1B;   // 16384
  int base = blockIdx.x * CH;
  for (int k = 0; k < CH / 1024; ++k) {
    int e = base + k * 1024 + tid;
    int s = ei[e];
    int d = ei[NE + e];
    unsigned at = (unsigned)((ea[(size_t)e * 3 + 0] & 1) |
                             ((ea[(size_t)e * 3 + 1] & 1) << 1) |
                             ((ea[(size_t)e * 3 + 2] & 1) << 2));
    int bt = d >> 9;
    int pos = atomicAdd(&lcnt[bt], 1);
    binned[lbase[bt] + pos] = (unsigned)s | ((unsigned)(d & 511) << 20) | (at << 29);
  }
}

// counting-sort each dst bucket by (local_dst<<2 | src_quartile); in-place;
// emits CSR row_ptr + byte-packed per-node cumulative quartile offsets (rpo).
__global__ void __launch_bounds__(256)
k_p3(unsigned* __restrict__ binned, const int* __restrict__ bucket_base,
     int* __restrict__ row_ptr, unsigned* __restrict__ rpo) {
  __shared__ int cnt[P3KEYS];       // 8 KB
  __shared__ int tsum[256];
  __shared__ unsigned stage[P3MAX]; // 20 KB
  int tid = threadIdx.x;
  int b = blockIdx.x;
  int s0 = bucket_base[b], s1 = bucket_base[b + 1];
  int len = s1 - s0;
  for (int i = tid; i < P3KEYS; i += 256) cnt[i] = 0;
  __syncthreads();
  for (int i = tid; i < len; i += 256) {
    unsigned rec = binned[s0 + i];
    int key = (int)((((rec >> 20) & 511u) << 2) | ((rec & 0xFFFFFu) >> 18));
    atomicAdd(&cnt[key], 1);
  }
  __syncthreads();
  int c[8];
  int run = 0;
#pragma unroll
  for (int k = 0; k < 8; ++k) { c[k] = cnt[tid * 8 + k]; run += c[k]; }
  tsum[tid] = run;
  __syncthreads();
  for (int off = 1; off < 256; off <<= 1) {
    int v = (tid >= off) ? tsum[tid - off] : 0;
    __syncthreads();
    tsum[tid] += v;
    __syncthreads();
  }
  int excl = tsum[tid] - run;
  int sum4 = c[0] + c[1] + c[2] + c[3];
  // thread tid owns local nodes 2*tid (keys 0-3) and 2*tid+1 (keys 4-7)
  row_ptr[b * NPB + 2 * tid] = s0 + excl;
  row_ptr[b * NPB + 2 * tid + 1] = s0 + excl + sum4;
  if (b == NB - 1 && tid == 255) row_ptr[NN] = s0 + excl + run;  // == NE
  {  // cumulative-inclusive quartile offsets, byte-packed (degree <= ~45 << 255)
    unsigned roA = 0, roB = 0;
    int rA = 0, rB = 0;
#pragma unroll
    for (int k = 0; k < 4; ++k) {
      rA += c[k];      roA |= (unsigned)rA << (k * 8);
      rB += c[4 + k];  roB |= (unsigned)rB << (k * 8);
    }
    rpo[(size_t)b * NPB + 2 * tid] = roA;
    rpo[(size_t)b * NPB + 2 * tid + 1] = roB;
  }
  int e = excl;
#pragma unroll
  for (int k = 0; k < 8; ++k) { cnt[tid * 8 + k] = e; e += c[k]; }
  __syncthreads();
  for (int i = tid; i < len; i += 256) {
    unsigned rec = binned[s0 + i];
    int key = (int)((((rec >> 20) & 511u) << 2) | ((rec & 0xFFFFFu) >> 18));
    int pos = atomicAdd(&cnt[key], 1);
    stage[pos] = rec & 0x00FFFFFFu | ((rec >> 29) << 20);
  }
  __syncthreads();
  for (int i = tid; i < len; i += 256) binned[s0 + i] = stage[i];
}

// ---------------- per-layer kernels ----------------

__device__ __forceinline__ void writeMirror(uint2* __restrict__ hmA,
                                            unsigned char* __restrict__ hmB,
                                            size_t n, const float* hv) {
  uint2 q;
  q.x = f8enc(hv[0]) | (f8enc(hv[1]) << 8) | (f8enc(hv[2]) << 16) | (f8enc(hv[3]) << 24);
  q.y = f8enc(hv[4]) | (f8enc(hv[5]) << 8) | (f8enc(hv[6]) << 16) | (f8enc(hv[7]) << 24);
  hmA[n] = q;
  hmB[n] = (unsigned char)f8enc(hv[8]);
}

// h_in(0) = atom embed sum; packed bf16 h; mirrors; vnsum0 = segsum
__global__ void k_atom(const float* __restrict__ atom_emb, const int* __restrict__ x,
                       const int* __restrict__ batch,
                       uv4* __restrict__ hb8, unsigned short* __restrict__ hb1,
                       uint2* __restrict__ hmA, unsigned char* __restrict__ hmB,
                       float* __restrict__ vnsum) {
  int n = blockIdx.x * 256 + threadIdx.x;
  int xi[9];
#pragma unroll
  for (int f = 0; f < 9; ++f) xi[f] = x[(size_t)n * 9 + f];
  float acc[DD] = {0.f,0.f,0.f,0.f,0.f,0.f,0.f,0.f,0.f};
#pragma unroll
  for (int f = 0; f < 9; ++f) {
    const float* row = atom_emb + ((size_t)f * 119 + xi[f]) * DD;
#pragma unroll
    for (int d = 0; d < DD; ++d) acc[d] += row[d];
  }
  pack9(hb8, hb1, (size_t)n, acc);
  writeMirror(hmA, hmB, (size_t)n, acc);
  int g = batch[n];
  int lane = threadIdx.x & 63;
  float s[DD];
#pragma unroll
  for (int d = 0; d < DD; ++d) s[d] = acc[d];
#pragma unroll
  for (int st = 1; st < 64; st <<= 1) {
    int gu = __shfl_up(g, st, 64);
    bool ok = (lane >= st) && (gu == g);
#pragma unroll
    for (int d = 0; d < DD; ++d) {
      float vu = __shfl_up(s[d], st, 64);
      if (ok) s[d] += vu;
    }
  }
  int gn = __shfl_down(g, 1, 64);
  if ((lane == 63) || (gn != g)) {
#pragma unroll
    for (int d = 0; d < DD; ++d) atomicAdd(&vnsum[(size_t)g * DD + d], s[d]);
  }
}

__device__ __forceinline__ void edgeDecodeAcc(unsigned r, uint2 q, unsigned db,
                                              const float* __restrict__ comb,
                                              float* __restrict__ acc) {
  const float* cb = comb + (r >> 20) * DD;
  float hv[DD] = {f8dec(q.x & 255u), f8dec((q.x >> 8) & 255u),
                  f8dec((q.x >> 16) & 255u), f8dec(q.x >> 24),
                  f8dec(q.y & 255u), f8dec((q.y >> 8) & 255u),
                  f8dec((q.y >> 16) & 255u), f8dec(q.y >> 24),
                  f8dec(db)};
#pragma unroll
  for (int d = 0; d < DD; ++d) {
    float m = hv[d] + cb[d];
    m = m > 0.f ? m : 0.f;
    acc[d] += m;
  }
}

// counted 4-deep pipelined sweep over [e0,e1)
__device__ __forceinline__ void accumNode(const unsigned* __restrict__ binned,
                                          int e0, int e1,
                                          const uint2* __restrict__ hmA,
                                          const unsigned char* __restrict__ hmB,
                                          const float* __restrict__ comb,
                                          float* __restrict__ acc) {
  int i = e0;
  for (; i + 4 <= e1; i += 4) {
    unsigned r0 = binned[i], r1 = binned[i + 1], r2 = binned[i + 2], r3 = binned[i + 3];
    uint2 q0 = hmA[r0 & 0xFFFFFu];
    uint2 q1 = hmA[r1 & 0xFFFFFu];
    uint2 q2 = hmA[r2 & 0xFFFFFu];
    uint2 q3 = hmA[r3 & 0xFFFFFu];
    unsigned char d0 = hmB[r0 & 0xFFFFFu];
    unsigned char d1 = hmB[r1 & 0xFFFFFu];
    unsigned char d2 = hmB[r2 & 0xFFFFFu];
    unsigned char d3 = hmB[r3 & 0xFFFFFu];
    edgeDecodeAcc(r0, q0, d0, comb, acc);
    edgeDecodeAcc(r1, q1, d1, comb, acc);
    edgeDecodeAcc(r2, q2, d2, comb, acc);
    edgeDecodeAcc(r3, q3, d3, comb, acc);
  }
  for (; i < e1; ++i) {
    unsigned r = binned[i];
    uint2 q = hmA[r & 0xFFFFFu];
    unsigned char db = hmB[r & 0xFFFFFu];
    edgeDecodeAcc(r, q, db, comb, acc);
  }
}

// Fused: CSR register-aggregate fp8-mirror messages; 4 barrier-paced COUNTED
// src-quartile phases; z=(1+eps)h_in+aggr -> X (packed bf16); BN1 stats (fp32)
__global__ void __launch_bounds__(256, 8)
k_edgeA(const uv4* __restrict__ hb8, const unsigned short* __restrict__ hb1,
        const uint2* __restrict__ hmA,
        const unsigned char* __restrict__ hmB, const unsigned* __restrict__ binned,
        const int* __restrict__ row_ptr, const unsigned* __restrict__ rpo,
        const float* __restrict__ bond,
        const float* __restrict__ W1l, const float* __restrict__ b1l,
        const float* __restrict__ epsp, uv4* __restrict__ X8,
        unsigned short* __restrict__ X1, float* __restrict__ stats) {
  __shared__ float comb[8 * DD];
  __shared__ float sW1[DD * HH], sb1[HH], ssum[HH], ssq[HH];
  int tid = threadIdx.x;
  for (int i = tid; i < DD * HH; i += 256) sW1[i] = W1l[i];
  if (tid < 8 * DD) {
    int c = tid / DD, d = tid % DD;
    comb[tid] = bond[(0 * 6 + (c & 1)) * DD + d] +
                bond[(1 * 6 + ((c >> 1) & 1)) * DD + d] +
                bond[(2 * 6 + ((c >> 2) & 1)) * DD + d];
  }
  if (tid < HH) { sb1[tid] = b1l[tid]; ssum[tid] = 0.f; ssq[tid] = 0.f; }
  __syncthreads();

  int b = blockIdx.x;
  int nA = b * NPB + tid;
  int nB = nA + 256;
  int ea0 = row_ptr[nA];
  int eb0 = row_ptr[nB];
  unsigned roA = rpo[nA], roB = rpo[nB];
  float acc0[DD] = {0.f,0.f,0.f,0.f,0.f,0.f,0.f,0.f,0.f};
  float acc1[DD] = {0.f,0.f,0.f,0.f,0.f,0.f,0.f,0.f,0.f};

  int pA = ea0, pB = eb0;
#pragma unroll
  for (int q = 0; q < 4; ++q) {
    int eA = ea0 + (int)((roA >> (q * 8)) & 255u);
    int eB = eb0 + (int)((roB >> (q * 8)) & 255u);
    accumNode(binned, pA, eA, hmA, hmB, comb, acc0);
    accumNode(binned, pB, eB, hmA, hmB, comb, acc1);
    pA = eA;
    pB = eB;
    __syncthreads();
  }

  float eps1 = 1.0f + epsp[0];
  float z0[DD], z1[DD];
  {
    float hi[DD];
    unpack9(hb8, hb1, (size_t)nA, hi);
#pragma unroll
    for (int d = 0; d < DD; ++d) z0[d] = eps1 * hi[d] + acc0[d];
    pack9(X8, X1, (size_t)nA, z0);
  }
  {
    float hi[DD];
    unpack9(hb8, hb1, (size_t)nB, hi);
#pragma unroll
    for (int d = 0; d < DD; ++d) z1[d] = eps1 * hi[d] + acc1[d];
    pack9(X8, X1, (size_t)nB, z1);
  }
  int lane0 = ((tid & 63) == 0);
#pragma unroll
  for (int j = 0; j < HH; ++j) {
    float a0 = sb1[j], a1 = sb1[j];
#pragma unroll
    for (int d = 0; d < DD; ++d) {
      a0 += z0[d] * sW1[d * HH + j];
      a1 += z1[d] * sW1[d * HH + j];
    }
    float rs = waveReduce(a0 + a1);
    float rq = waveReduce(a0 * a0 + a1 * a1);
    if (lane0) { atomicAdd(&ssum[j], rs); atomicAdd(&ssq[j], rq); }
  }
  __syncthreads();
  int copy = (b & 63) * 64;
  if (tid < HH) {
    atomicAdd(&stats[copy + NSUM1 + tid], ssum[tid]);
    atomicAdd(&stats[copy + NSQ1 + tid], ssq[tid]);
  }
}

// in-place X (packed bf16): z2 = relu(bn1(z@W1+b1)) @ W2 + b2;  BN2 stats (spread)
__global__ void __launch_bounds__(256)
k_partB(uv4* __restrict__ X8, unsigned short* __restrict__ X1,
        const float* __restrict__ W1l, const float* __restrict__ b1l,
        const float* __restrict__ g1, const float* __restrict__ be1,
        const float* __restrict__ W2l, const float* __restrict__ b2l,
        float* __restrict__ stats) {
  __shared__ float sW1[DD * HH], sW2[HH * DD], sb1[HH], sb2[DD];
  __shared__ float sc1[HH], sh1[HH], ssum[DD], ssq[DD];
  int tid = threadIdx.x;
  for (int i = tid; i < DD * HH; i += 256) sW1[i] = W1l[i];
  for (int i = tid; i < HH * DD; i += 256) sW2[i] = W2l[i];
  if (tid < HH) {
    float s = 0.f, q = 0.f;
#pragma unroll
    for (int c = 0; c < 64; ++c) {
      s += stats[c * 64 + NSUM1 + tid];
      q += stats[c * 64 + NSQ1 + tid];
    }
    float mean = s * (1.0f / NN);
    float var = q * (1.0f / NN) - mean * mean;
    float sc = g1[tid] * rsqrtf(var + BN_EPS);
    sc1[tid] = sc;
    sh1[tid] = be1[tid] - mean * sc;
    sb1[tid] = b1l[tid];
  }
  if (tid < DD) { sb2[tid] = b2l[tid]; ssum[tid] = 0.f; ssq[tid] = 0.f; }
  __syncthreads();
  size_t n = (size_t)blockIdx.x * 256 + tid;
  float z[DD];
  unpack9(X8, X1, n, z);
  float t[HH];
#pragma unroll
  for (int j = 0; j < HH; ++j) {
    float a = sb1[j];
#pragma unroll
    for (int d = 0; d < DD; ++d) a += z[d] * sW1[d * HH + j];
    a = a * sc1[j] + sh1[j];
    t[j] = a > 0.f ? a : 0.f;
  }
  float z2[DD];
  int lane0 = ((tid & 63) == 0);
#pragma unroll
  for (int d = 0; d < DD; ++d) {
    float a = sb2[d];
#pragma unroll
    for (int j = 0; j < HH; ++j) a += t[j] * sW2[j * DD + d];
    z2[d] = a;
    float rs = waveReduce(a);
    float rq = waveReduce(a * a);
    if (lane0) { atomicAdd(&ssum[d], rs); atomicAdd(&ssq[d], rq); }
  }
  pack9(X8, X1, n, z2);
  __syncthreads();
  int copy = ((int)blockIdx.x & 63) * 64;
  if (tid < DD) {
    atomicAdd(&stats[copy + NSUM2 + tid], ssum[tid]);
    atomicAdd(&stats[copy + NSQ2 + tid], ssq[tid]);
  }
}

// h_new = bn2(z2)[relu] + h_in; vn add + packed h + mirrors; last: spread out-sums
__global__ void __launch_bounds__(256)
k_partC(const uv4* __restrict__ X8, const unsigned short* __restrict__ X1,
        uv4* __restrict__ hb8, unsigned short* __restrict__ hb1,
        uint2* __restrict__ hmA, unsigned char* __restrict__ hmB,
        float* __restrict__ stats, const float* __restrict__ g2,
        const float* __restrict__ be2, const int* __restrict__ batch,
        const float* __restrict__ vn_next, float* __restrict__ vnsum_out,
        int do_relu) {
  __shared__ float sc[DD], sh[DD], ssum[DD];
  int tid = threadIdx.x;
  if (tid < DD) {
    float s = 0.f, q = 0.f;
#pragma unroll
    for (int c = 0; c < 64; ++c) {
      s += stats[c * 64 + NSUM2 + tid];
      q += stats[c * 64 + NSQ2 + tid];
    }
    float mean = s * (1.0f / NN);
    float var = q * (1.0f / NN) - mean * mean;
    float sg = g2[tid] * rsqrtf(var + BN_EPS);
    sc[tid] = sg;
    sh[tid] = be2[tid] - mean * sg;
    ssum[tid] = 0.f;
  }
  __syncthreads();
  size_t n = (size_t)blockIdx.x * 256 + tid;
  float zv[DD];
  unpack9(X8, X1, n, zv);
  float hi[DD];
  unpack9(hb8, hb1, n, hi);
  float hv[DD];
#pragma unroll
  for (int d = 0; d < DD; ++d) {
    float z = zv[d] * sc[d] + sh[d];
    if (do_relu) z = z > 0.f ? z : 0.f;
    hv[d] = z + hi[d];
  }
  if (vn_next != nullptr) {
    int g = batch[n];
#pragma unroll
    for (int d = 0; d < DD; ++d) hv[d] += vn_next[(size_t)g * DD + d];
    pack9(hb8, hb1, n, hv);
    writeMirror(hmA, hmB, n, hv);
    if (vnsum_out != nullptr) {
      int lane = tid & 63;
      float s[DD];
#pragma unroll
      for (int d = 0; d < DD; ++d) s[d] = hv[d];
#pragma unroll
      for (int st = 1; st < 64; st <<= 1) {
        int gu = __shfl_up(g, st, 64);
        bool ok = (lane >= st) && (gu == g);
#pragma unroll
        for (int d = 0; d < DD; ++d) {
          float vu = __shfl_up(s[d], st, 64);
          if (ok) s[d] += vu;
        }
      }
      int gn = __shfl_down(g, 1, 64);
      if ((lane == 63) || (gn != g)) {
#pragma unroll
        for (int d = 0; d < DD; ++d) atomicAdd(&vnsum_out[(size_t)g * DD + d], s[d]);
      }
    }
  } else {
    int lane0 = ((tid & 63) == 0);
#pragma unroll
    for (int d = 0; d < DD; ++d) {
      float r = waveReduce(hv[d]);
      if (lane0) atomicAdd(&ssum[d], r);
    }
    __syncthreads();
    int copy = ((int)blockIdx.x & 63) * 64;
    if (tid < DD) atomicAdd(&stats[copy + OUTS + tid], ssum[tid]);
  }
}

// reduce spread out-sums -> d_out
__global__ void k_out(const float* __restrict__ stats, float* __restrict__ out) {
  int tid = threadIdx.x;
  if (tid < DD) {
    float s = 0.f;
#pragma unroll
    for (int c = 0; c < 64; ++c) s += stats[c * 64 + OUTS + tid];
    out[tid] = s;
  }
}

// ---------------- fused virtual-node MLP (grid-sync via spin barrier) ----------------
// VNB=128 blocks <= CU count -> all co-resident; barrier slots zeroed by the
// per-layer stats memset; gen is read BEFORE arrival so no block can spin on a
// post-bump value; post-barrier stat reads use device-scope RMW (atomicAdd 0).

__device__ __forceinline__ void gridBar(int* cnt, int* gen) {
  __syncthreads();
  if (threadIdx.x == 0) {
    __threadfence();
    int g = atomicAdd(gen, 0);
    __threadfence();
    int t = atomicAdd(cnt, 1 | (g >> 31));   // data-dep: g read precedes arrival
    if (t == VNB - 1) {
      atomicAdd(gen, 1);
    } else {
      while (atomicAdd(gen, 0) == g) __builtin_amdgcn_s_sleep(8);
    }
    __threadfence();
  }
  __syncthreads();
}

__global__ void __launch_bounds__(256)
k_vn(const float* __restrict__ vnsum, float* __restrict__ vn,
     const float* __restrict__ W1l, const float* __restrict__ b1l,
     const float* __restrict__ g1, const float* __restrict__ be1,
     const float* __restrict__ W2l, const float* __restrict__ b2l,
     const float* __restrict__ g2, const float* __restrict__ be2,
     float* __restrict__ stats) {
  __shared__ float sW1[DD * HH], sW2[HH * DD], sb1[HH], sb2[DD];
  __shared__ float ssum[HH], ssq[HH], sc1[HH], sh1[HH];
  int tid = threadIdx.x;
  int* bar = (int*)(stats + BARS);
  for (int i = tid; i < DD * HH; i += 256) { sW1[i] = W1l[i]; sW2[i] = W2l[i]; }
  if (tid < HH) { sb1[tid] = b1l[tid]; ssum[tid] = 0.f; ssq[tid] = 0.f; }
  if (tid < DD) sb2[tid] = b2l[tid];
  __syncthreads();
  size_t g = (size_t)blockIdx.x * 256 + tid;
  float r[DD];
#pragma unroll
  for (int d = 0; d < DD; ++d) r[d] = vnsum[g * DD + d] + vn[g * DD + d];
  int lane0 = ((tid & 63) == 0);
  float a1[HH];
#pragma unroll
  for (int j = 0; j < HH; ++j) {
    float a = sb1[j];
#pragma unroll
    for (int d = 0; d < DD; ++d) a += r[d] * sW1[d * HH + j];
    a1[j] = a;
    float rs = waveReduce(a);
    float rq = waveReduce(a * a);
    if (lane0) { atomicAdd(&ssum[j], rs); atomicAdd(&ssq[j], rq); }
  }
  __syncthreads();
  if (tid < HH) {
    atomicAdd(&stats[VSUM1 + tid], ssum[tid]);
    atomicAdd(&stats[VSQ1 + tid], ssq[tid]);
  }
  gridBar(&bar[0], &bar[1]);
  if (tid < HH) {
    float s = atomicAdd(&stats[VSUM1 + tid], 0.0f);   // device-coherent read
    float q = atomicAdd(&stats[VSQ1 + tid], 0.0f);
    float mean = s * (1.0f / NG);
    float var = q * (1.0f / NG) - mean * mean;
    float sc = g1[tid] * rsqrtf(var + BN_EPS);
    sc1[tid] = sc;
    sh1[tid] = be1[tid] - mean * sc;
  }
  if (tid < DD) { ssum[tid] = 0.f; ssq[tid] = 0.f; }
  __syncthreads();
  float t[HH];
#pragma unroll
  for (int j = 0; j < HH; ++j) {
    float a = a1[j] * sc1[j] + sh1[j];
    t[j] = a > 0.f ? a : 0.f;
  }
  float z2[DD];
#pragma unroll
  for (int d = 0; d < DD; ++d) {
    float a = sb2[d];
#pragma unroll
    for (int j = 0; j < HH; ++j) a += t[j] * sW2[j * DD + d];
    z2[d] = a;
    float rs = waveReduce(a);
    float rq = waveReduce(a * a);
    if (lane0) { atomicAdd(&ssum[d], rs); atomicAdd(&ssq[d], rq); }
  }
  __syncthreads();
  if (tid < DD) {
    atomicAdd(&stats[VSUM2 + tid], ssum[tid]);
    atomicAdd(&stats[VSQ2 + tid], ssq[tid]);
  }
  gridBar(&bar[2], &bar[3]);
  if (tid < DD) {
    float s = atomicAdd(&stats[VSUM2 + tid], 0.0f);
    float q = atomicAdd(&stats[VSQ2 + tid], 0.0f);
    float mean = s * (1.0f / NG);
    float var = q * (1.0f / NG) - mean * mean;
    float sc = g2[tid] * rsqrtf(var + BN_EPS);
    sc1[tid] = sc;                 // reuse as sc2/sh2
    sh1[tid] = be2[tid] - mean * sc;
  }
  __syncthreads();
#pragma unroll
  for (int d = 0; d < DD; ++d) {
    float v = z2[d] * sc1[d] + sh1[d];
    v = v > 0.f ? v : 0.f;
    vn[g * DD + d] += v;
  }
}

extern "C" void kernel_launch(void* const* d_in, const int* in_sizes, int n_in,
                              void* d_out, int out_size, void* d_ws, size_t ws_size,
                              hipStream_t stream) {
  const float* atom_emb = (const float*)d_in[0];
  const float* bond_emb = (const float*)d_in[1];
  const float* eps_gin  = (const float*)d_in[2];
  const float* W1   = (const float*)d_in[3];
  const float* b1   = (const float*)d_in[4];
  const float* bn1_g = (const float*)d_in[5];
  const float* bn1_b = (const float*)d_in[6];
  const float* W2   = (const float*)d_in[7];
  const float* b2   = (const float*)d_in[8];
  const float* bno_g = (const float*)d_in[9];
  const float* bno_b = (const float*)d_in[10];
  const float* vnW1 = (const float*)d_in[11];
  const float* vnb1 = (const float*)d_in[12];
  const float* vnbn1_g = (const float*)d_in[13];
  const float* vnbn1_b = (const float*)d_in[14];
  const float* vnW2 = (const float*)d_in[15];
  const float* vnb2 = (const float*)d_in[16];
  const float* vnbn2_g = (const float*)d_in[17];
  const float* vnbn2_b = (const float*)d_in[18];
  const int* x          = (const int*)d_in[19];
  const int* edge_index = (const int*)d_in[20];
  const int* edge_attr  = (const int*)d_in[21];
  const int* batch      = (const int*)d_in[22];
  float* out = (float*)d_out;

  // workspace layout — ~91 MB.
  // Region 0: union of transient blkcnt (NB*P1B ints, 4 MB) + cnt_pad (128 KB)
  // with persistent hb8/hb1/X8/X1 packed bf16 node streams (37.75 MB, live
  // from k_atom, i.e. after all transient users are done).
  char* base = (char*)d_ws;
  uv4* hb8 = (uv4*)base;                                 // NN uint4
  unsigned short* hb1 = (unsigned short*)(hb8 + (size_t)NN);
  uv4* X8 = (uv4*)(hb1 + (size_t)NN);                    // NN uint4
  unsigned short* X1 = (unsigned short*)(X8 + (size_t)NN);
  int* blkcnt  = (int*)base;                             // NB*P1B (transient)
  int* cnt_pad = blkcnt + (size_t)NB * P1B;              // NB*16 (transient)
  char* pers = (char*)(X1 + (size_t)NN);
  uint2* hmA   = (uint2*)pers;                           // NN uint2 (8 MB)
  unsigned char* hmB = (unsigned char*)(hmA + (size_t)NN);  // NN bytes (1 MB)
  unsigned* binned = (unsigned*)(hmB + (size_t)NN);      // NE u32 (33.5 MB)
  float* vn    = (float*)(binned + (size_t)NE);          // NG*DD
  float* vnsum = vn + (size_t)NG * DD;                   // NG*DD
  float* stats = vnsum + (size_t)NG * DD;                // STATS_FLOATS
  int* bucket_base = (int*)(stats + STATS_FLOATS);       // NB+1
  int* row_ptr     = bucket_base + NB + 1;               // NN+1 (4 MB)
  unsigned* rpo    = (unsigned*)(row_ptr + NN + 1);      // NN u32 (4 MB)

  // ---- one-time binning (single-pass deterministic scatter) ----
  (void)hipMemsetAsync(cnt_pad, 0, (size_t)NB * 16 * sizeof(int), stream);
  k_counthist<<<P1B, 1024, 0, stream>>>(edge_index, cnt_pad, blkcnt);
  k_scan<<<1, 256, 0, stream>>>(cnt_pad, bucket_base);
  k_scanB<<<NB, 256, 0, stream>>>(blkcnt, bucket_base);
  k_p1<<<P1B, 1024, 0, stream>>>(edge_index, edge_attr, blkcnt, binned);
  k_p3<<<NB, 256, 0, stream>>>(binned, bucket_base, row_ptr, rpo);

  (void)hipMemsetAsync(vn, 0, (size_t)2 * NG * DD * sizeof(float), stream);
  k_atom<<<NN / 256, 256, 0, stream>>>(atom_emb, x, batch, hb8, hb1, hmA, hmB, vnsum);

  for (int l = 0; l < 3; ++l) {
    int has_vn = (l < 2);
    (void)hipMemsetAsync(stats, 0, STATS_FLOATS * sizeof(float), stream);
    if (has_vn) {
      k_vn<<<VNB, 256, 0, stream>>>(vnsum, vn,
                                    vnW1 + (size_t)l * DD * HH, vnb1 + (size_t)l * HH,
                                    vnbn1_g + (size_t)l * HH, vnbn1_b + (size_t)l * HH,
                                    vnW2 + (size_t)l * HH * DD, vnb2 + (size_t)l * DD,
                                    vnbn2_g + (size_t)l * DD, vnbn2_b + (size_t)l * DD,
                                    stats);
    }
    k_edgeA<<<NB, 256, 0, stream>>>(hb8, hb1, hmA, hmB, binned, row_ptr, rpo,
                                    bond_emb + (size_t)l * 3 * 6 * DD,
                                    W1 + (size_t)l * DD * HH, b1 + (size_t)l * HH,
                                    eps_gin + l, X8, X1, stats);
    k_partB<<<NN / 256, 256, 0, stream>>>(X8, X1, W1 + (size_t)l * DD * HH,
                                          b1 + (size_t)l * HH,
                                          bn1_g + (size_t)l * HH, bn1_b + (size_t)l * HH,
                                          W2 + (size_t)l * HH * DD, b2 + (size_t)l * DD,
                                          stats);
    if (l == 0)
      (void)hipMemsetAsync(vnsum, 0, (size_t)NG * DD * sizeof(float), stream);
    k_partC<<<NN / 256, 256, 0, stream>>>(X8, X1, hb8, hb1, hmA, hmB, stats,
                                          bno_g + (size_t)l * DD, bno_b + (size_t)l * DD,
                                          batch,
                                          has_vn ? vn : nullptr,
                                          (l == 0) ? vnsum : nullptr,
                                          has_vn ? 1 : 0);
  }
  k_out<<<1, 64, 0, stream>>>(stats, out);
}

// Round 12
// 1264.251 us; speedup vs baseline: 1.0757x; 1.0757x over previous
//
#include <hip/hip_runtime.h>
#include <hip/hip_fp8.h>

#define NN 1048576   // nodes (= 2^20, src fits 20 bits)
#define NE 8388608   // edges
#define NG 32768     // graphs
#define DD 9         // emb dim
#define HH 18        // hidden
#define BN_EPS 1e-5f

#define NPB 512      // nodes per dst bucket
#define NB  2048     // dst buckets
#define NGRP 64      // coarse dst-groups
#define P1B 512      // k_p1 / counthist blocks
#define P3MAX 5120   // max edges per bucket staged in k_p3 (Poisson(4096), safe)
#define P3KEYS 2048  // 512 nodes x 4 src-quartiles
#define VNB 128      // k_vn blocks (<= CU count -> co-resident, spin barrier safe)

// spread stats: 64 copies x 64 chans. within-copy offsets:
#define NSUM1 0      // 18
#define NSQ1  18     // 18
#define NSUM2 36     // 9
#define NSQ2  45     // 9
#define OUTS  54     // 9
#define VBASE 4096   // VN stats (single copy)
#define VSUM1 (VBASE+0)
#define VSQ1  (VBASE+18)
#define VSUM2 (VBASE+36)
#define VSQ2  (VBASE+45)
#define BARS  4160   // 4 ints: {cnt0,gen0,cnt1,gen1}, zeroed by stats memset
#define STATS_FLOATS 4224

typedef float fv4 __attribute__((ext_vector_type(4)));
typedef unsigned uv4 __attribute__((ext_vector_type(4)));

__device__ __forceinline__ float waveReduce(float v) {
#pragma unroll
  for (int off = 32; off > 0; off >>= 1) v += __shfl_down(v, off, 64);
  return v;
}
__device__ __forceinline__ unsigned f8enc(float f) {
  __hip_fp8_e4m3 v(f);
  return (unsigned)v.__x;
}
__device__ __forceinline__ float f8dec(unsigned b) {
  __hip_fp8_e4m3 v;
  v.__x = (__hip_fp8_storage_t)b;
  return (float)v;
}
// bf16 round-to-nearest-even pack/unpack
__device__ __forceinline__ unsigned bf16r(float x) {
  unsigned u = __float_as_uint(x);
  unsigned r = u + 0x7FFFu + ((u >> 16) & 1u);
  return r >> 16;
}
__device__ __forceinline__ unsigned pk2(float a, float b) {
  return bf16r(a) | (bf16r(b) << 16);
}
__device__ __forceinline__ float lo16(unsigned u) { return __uint_as_float(u << 16); }
__device__ __forceinline__ float hi16(unsigned u) { return __uint_as_float(u & 0xFFFF0000u); }

__device__ __forceinline__ void pack9(uv4* __restrict__ b8, unsigned short* __restrict__ b1,
                                      size_t n, const float* v) {
  uv4 p;
  p.x = pk2(v[0], v[1]); p.y = pk2(v[2], v[3]);
  p.z = pk2(v[4], v[5]); p.w = pk2(v[6], v[7]);
  __builtin_nontemporal_store(p, &b8[n]);
  __builtin_nontemporal_store((unsigned short)bf16r(v[8]), &b1[n]);
}
__device__ __forceinline__ void unpack9(const uv4* __restrict__ b8,
                                        const unsigned short* __restrict__ b1,
                                        size_t n, float* v) {
  uv4 P = __builtin_nontemporal_load(&b8[n]);
  unsigned short s = b1[n];
  v[0] = lo16(P.x); v[1] = hi16(P.x); v[2] = lo16(P.y); v[3] = hi16(P.y);
  v[4] = lo16(P.z); v[5] = hi16(P.z); v[6] = lo16(P.w); v[7] = hi16(P.w);
  v[8] = __uint_as_float((unsigned)s << 16);
}

// ---------------- binning (once per launch) ----------------
// PROVEN two-pass deterministic counting-sort (round-10 structure; the
// round-11 single-pass scatter was 7x write-amplified — reverted).
// counthist/scan/scanG -> deterministic per-(block,group) bases; p1 scatters
// 8B records into 64 coarse group streams; p2 -> 32 fine buckets per group
// (LDS-staged, coalesced); p3 sorts each bucket by (local_dst, src_quartile)
// and emits CSR row_ptr + byte-packed quartile offsets (rpo).

__global__ void __launch_bounds__(1024)
k_counthist(const int* __restrict__ ei, int* __restrict__ cnt_pad,
            int* __restrict__ blkcnt) {
  __shared__ int hist[NB];   // 8 KB
  int tid = threadIdx.x;
  for (int i = tid; i < NB; i += 1024) hist[i] = 0;
  __syncthreads();
  const int CH = NE / P1B;   // 16384
  int base = blockIdx.x * CH;
  for (int i = tid; i < CH; i += 1024)
    atomicAdd(&hist[ei[NE + base + i] >> 9], 1);
  __syncthreads();
  for (int i = tid; i < NB; i += 1024)
    if (hist[i]) atomicAdd(&cnt_pad[i * 16], hist[i]);
  if (tid < NGRP) {
    int s = 0;
#pragma unroll
    for (int k = 0; k < 32; ++k) s += hist[tid * 32 + k];
    blkcnt[tid * P1B + blockIdx.x] = s;
  }
}

__global__ void k_scan(const int* __restrict__ cnt_pad, int* __restrict__ bucket_base,
                       int* __restrict__ bucket_cursor) {
  __shared__ int tsum[256];
  int tid = threadIdx.x;
  int c[8];
  int run = 0;
#pragma unroll
  for (int k = 0; k < 8; ++k) { c[k] = cnt_pad[(tid * 8 + k) * 16]; run += c[k]; }
  tsum[tid] = run;
  __syncthreads();
  for (int off = 1; off < 256; off <<= 1) {
    int v = (tid >= off) ? tsum[tid - off] : 0;
    __syncthreads();
    tsum[tid] += v;
    __syncthreads();
  }
  int excl = tsum[tid] - run;
#pragma unroll
  for (int k = 0; k < 8; ++k) {
    bucket_base[tid * 8 + k] = excl;
    bucket_cursor[tid * 8 + k] = excl;
    excl += c[k];
  }
  if (tid == 255) bucket_base[NB] = tsum[255];
}

// per-group exclusive scan of the P1B block counts -> write bases (in place)
__global__ void k_scanG(int* __restrict__ blkcnt, const int* __restrict__ bucket_base) {
  __shared__ int tsum[256];
  int tid = threadIdx.x;
  int g = blockIdx.x;
  int c0 = blkcnt[g * P1B + 2 * tid], c1 = blkcnt[g * P1B + 2 * tid + 1];
  int run = c0 + c1;
  tsum[tid] = run;
  __syncthreads();
  for (int off = 1; off < 256; off <<= 1) {
    int v = (tid >= off) ? tsum[tid - off] : 0;
    __syncthreads();
    tsum[tid] += v;
    __syncthreads();
  }
  int excl = tsum[tid] - run + bucket_base[g << 5];
  blkcnt[g * P1B + 2 * tid] = excl;
  blkcnt[g * P1B + 2 * tid + 1] = excl + c0;
}

__global__ void __launch_bounds__(1024)
k_p1(const int* __restrict__ ei, const int* __restrict__ ea,
     const int* __restrict__ blkcnt, uint2* __restrict__ coarse) {
  __shared__ int lcnt[NGRP];
  __shared__ int lbase[NGRP];
  int tid = threadIdx.x;
  if (tid < NGRP) { lcnt[tid] = 0; lbase[tid] = blkcnt[tid * P1B + blockIdx.x]; }
  __syncthreads();
  const int CH = NE / P1B;   // 16384
  int base = blockIdx.x * CH;
  for (int k = 0; k < CH / 1024; ++k) {
    int e = base + k * 1024 + tid;
    int s = ei[e];
    int d = ei[NE + e];
    unsigned at = (unsigned)((ea[(size_t)e * 3 + 0] & 1) |
                             ((ea[(size_t)e * 3 + 1] & 1) << 1) |
                             ((ea[(size_t)e * 3 + 2] & 1) << 2));
    int g = d >> 14;
    int pos = atomicAdd(&lcnt[g], 1);
    coarse[lbase[g] + pos] = make_uint2((unsigned)s | (at << 20), (unsigned)d);
  }
}

#define P2K 48
#define P2SUB 32
__global__ void __launch_bounds__(256)
k_p2(const uint2* __restrict__ coarse, const int* __restrict__ bucket_base,
     int* __restrict__ bucket_cursor, unsigned* __restrict__ binned) {
  __shared__ unsigned stage[32 * P2K];
  __shared__ int scnt[32], gbase[32];
  int tid = threadIdx.x;
  int g = blockIdx.x >> 5;
  int sub = blockIdx.x & 31;
  int s0 = bucket_base[g << 5];
  int s1 = bucket_base[(g + 1) << 5];
  int len = s1 - s0;
  int chunk = (len + P2SUB - 1) >> 5;
  int my0 = s0 + sub * chunk;
  int my1 = min(my0 + chunk, s1);
  if (tid < 32) scnt[tid] = 0;
  __syncthreads();
  for (int b0 = my0; b0 < my1; b0 += 1024) {
#pragma unroll
    for (int k = 0; k < 4; ++k) {
      int i = b0 + k * 256 + tid;
      if (i < my1) {
        uint2 rec = coarse[i];
        unsigned s = rec.x & 0xFFFFFu;
        unsigned at = rec.x >> 20;
        unsigned d = rec.y;
        int bt = (int)((d >> 9) & 31u);
        unsigned o = s | ((d & 511u) << 20) | (at << 29);
        int pos = atomicAdd(&scnt[bt], 1);
        if (pos < P2K) stage[bt * P2K + pos] = o;
        else binned[atomicAdd(&bucket_cursor[(g << 5) | bt], 1)] = o;
      }
    }
    __syncthreads();
    {
      int bt = tid >> 3, j = tid & 7;
      int cnt = min(scnt[bt], P2K);
      if (j == 0) gbase[bt] = cnt ? atomicAdd(&bucket_cursor[(g << 5) | bt], cnt) : 0;
      __syncthreads();
      for (int i = j; i < cnt; i += 8) binned[gbase[bt] + i] = stage[bt * P2K + i];
    }
    __syncthreads();
    if (tid < 32) scnt[tid] = 0;
    __syncthreads();
  }
}

// counting-sort each dst bucket by (local_dst<<2 | src_quartile); in-place;
// emits CSR row_ptr + byte-packed per-node cumulative quartile offsets (rpo).
// Final record: src (bits 0-19) | attr (bits 20-22).
__global__ void __launch_bounds__(256)
k_p3(unsigned* __restrict__ binned, const int* __restrict__ bucket_base,
     int* __restrict__ row_ptr, unsigned* __restrict__ rpo) {
  __shared__ int cnt[P3KEYS];       // 8 KB
  __shared__ int tsum[256];
  __shared__ unsigned stage[P3MAX]; // 20 KB
  int tid = threadIdx.x;
  int b = blockIdx.x;
  int s0 = bucket_base[b], s1 = bucket_base[b + 1];
  int len = s1 - s0;
  for (int i = tid; i < P3KEYS; i += 256) cnt[i] = 0;
  __syncthreads();
  for (int i = tid; i < len; i += 256) {
    unsigned rec = binned[s0 + i];
    int key = (int)((((rec >> 20) & 511u) << 2) | ((rec & 0xFFFFFu) >> 18));
    atomicAdd(&cnt[key], 1);
  }
  __syncthreads();
  int c[8];
  int run = 0;
#pragma unroll
  for (int k = 0; k < 8; ++k) { c[k] = cnt[tid * 8 + k]; run += c[k]; }
  tsum[tid] = run;
  __syncthreads();
  for (int off = 1; off < 256; off <<= 1) {
    int v = (tid >= off) ? tsum[tid - off] : 0;
    __syncthreads();
    tsum[tid] += v;
    __syncthreads();
  }
  int excl = tsum[tid] - run;
  int sum4 = c[0] + c[1] + c[2] + c[3];
  // thread tid owns local nodes 2*tid (keys 0-3) and 2*tid+1 (keys 4-7)
  row_ptr[b * NPB + 2 * tid] = s0 + excl;
  row_ptr[b * NPB + 2 * tid + 1] = s0 + excl + sum4;
  if (b == NB - 1 && tid == 255) row_ptr[NN] = s0 + excl + run;  // == NE
  {  // cumulative-inclusive quartile offsets, byte-packed (degree <= ~45 << 255)
    unsigned roA = 0, roB = 0;
    int rA = 0, rB = 0;
#pragma unroll
    for (int k = 0; k < 4; ++k) {
      rA += c[k];      roA |= (unsigned)rA << (k * 8);
      rB += c[4 + k];  roB |= (unsigned)rB << (k * 8);
    }
    rpo[(size_t)b * NPB + 2 * tid] = roA;
    rpo[(size_t)b * NPB + 2 * tid + 1] = roB;
  }
  int e = excl;
#pragma unroll
  for (int k = 0; k < 8; ++k) { cnt[tid * 8 + k] = e; e += c[k]; }
  __syncthreads();
  for (int i = tid; i < len; i += 256) {
    unsigned rec = binned[s0 + i];
    int key = (int)((((rec >> 20) & 511u) << 2) | ((rec & 0xFFFFFu) >> 18));
    int pos = atomicAdd(&cnt[key], 1);
    stage[pos] = (rec & 0xFFFFFu) | ((rec >> 29) << 20);
  }
  __syncthreads();
  for (int i = tid; i < len; i += 256) binned[s0 + i] = stage[i];
}

// ---------------- per-layer kernels ----------------

__device__ __forceinline__ void writeMirror(uint2* __restrict__ hmA,
                                            unsigned char* __restrict__ hmB,
                                            size_t n, const float* hv) {
  uint2 q;
  q.x = f8enc(hv[0]) | (f8enc(hv[1]) << 8) | (f8enc(hv[2]) << 16) | (f8enc(hv[3]) << 24);
  q.y = f8enc(hv[4]) | (f8enc(hv[5]) << 8) | (f8enc(hv[6]) << 16) | (f8enc(hv[7]) << 24);
  hmA[n] = q;
  hmB[n] = (unsigned char)f8enc(hv[8]);
}

// h_in(0) = atom embed sum; packed bf16 h; mirrors; vnsum0 = segsum
__global__ void k_atom(const float* __restrict__ atom_emb, const int* __restrict__ x,
                       const int* __restrict__ batch,
                       uv4* __restrict__ hb8, unsigned short* __restrict__ hb1,
                       uint2* __restrict__ hmA, unsigned char* __restrict__ hmB,
                       float* __restrict__ vnsum) {
  int n = blockIdx.x * 256 + threadIdx.x;
  int xi[9];
#pragma unroll
  for (int f = 0; f < 9; ++f) xi[f] = x[(size_t)n * 9 + f];
  float acc[DD] = {0.f,0.f,0.f,0.f,0.f,0.f,0.f,0.f,0.f};
#pragma unroll
  for (int f = 0; f < 9; ++f) {
    const float* row = atom_emb + ((size_t)f * 119 + xi[f]) * DD;
#pragma unroll
    for (int d = 0; d < DD; ++d) acc[d] += row[d];
  }
  pack9(hb8, hb1, (size_t)n, acc);
  writeMirror(hmA, hmB, (size_t)n, acc);
  int g = batch[n];
  int lane = threadIdx.x & 63;
  float s[DD];
#pragma unroll
  for (int d = 0; d < DD; ++d) s[d] = acc[d];
#pragma unroll
  for (int st = 1; st < 64; st <<= 1) {
    int gu = __shfl_up(g, st, 64);
    bool ok = (lane >= st) && (gu == g);
#pragma unroll
    for (int d = 0; d < DD; ++d) {
      float vu = __shfl_up(s[d], st, 64);
      if (ok) s[d] += vu;
    }
  }
  int gn = __shfl_down(g, 1, 64);
  if ((lane == 63) || (gn != g)) {
#pragma unroll
    for (int d = 0; d < DD; ++d) atomicAdd(&vnsum[(size_t)g * DD + d], s[d]);
  }
}

__device__ __forceinline__ void edgeDecodeAcc(unsigned r, uint2 q, unsigned db,
                                              const float* __restrict__ comb,
                                              float* __restrict__ acc) {
  const float* cb = comb + (r >> 20) * DD;
  float hv[DD] = {f8dec(q.x & 255u), f8dec((q.x >> 8) & 255u),
                  f8dec((q.x >> 16) & 255u), f8dec(q.x >> 24),
                  f8dec(q.y & 255u), f8dec((q.y >> 8) & 255u),
                  f8dec((q.y >> 16) & 255u), f8dec(q.y >> 24),
                  f8dec(db)};
#pragma unroll
  for (int d = 0; d < DD; ++d) {
    float m = hv[d] + cb[d];
    m = m > 0.f ? m : 0.f;
    acc[d] += m;
  }
}

// counted 4-deep pipelined sweep over [e0,e1)
__device__ __forceinline__ void accumNode(const unsigned* __restrict__ binned,
                                          int e0, int e1,
                                          const uint2* __restrict__ hmA,
                                          const unsigned char* __restrict__ hmB,
                                          const float* __restrict__ comb,
                                          float* __restrict__ acc) {
  int i = e0;
  for (; i + 4 <= e1; i += 4) {
    unsigned r0 = binned[i], r1 = binned[i + 1], r2 = binned[i + 2], r3 = binned[i + 3];
    uint2 q0 = hmA[r0 & 0xFFFFFu];
    uint2 q1 = hmA[r1 & 0xFFFFFu];
    uint2 q2 = hmA[r2 & 0xFFFFFu];
    uint2 q3 = hmA[r3 & 0xFFFFFu];
    unsigned char d0 = hmB[r0 & 0xFFFFFu];
    unsigned char d1 = hmB[r1 & 0xFFFFFu];
    unsigned char d2 = hmB[r2 & 0xFFFFFu];
    unsigned char d3 = hmB[r3 & 0xFFFFFu];
    edgeDecodeAcc(r0, q0, d0, comb, acc);
    edgeDecodeAcc(r1, q1, d1, comb, acc);
    edgeDecodeAcc(r2, q2, d2, comb, acc);
    edgeDecodeAcc(r3, q3, d3, comb, acc);
  }
  for (; i < e1; ++i) {
    unsigned r = binned[i];
    uint2 q = hmA[r & 0xFFFFFu];
    unsigned char db = hmB[r & 0xFFFFFu];
    edgeDecodeAcc(r, q, db, comb, acc);
  }
}

// Fused: CSR register-aggregate fp8-mirror messages; 4 barrier-paced COUNTED
// src-quartile phases; z=(1+eps)h_in+aggr -> X (packed bf16); BN1 stats (fp32)
__global__ void __launch_bounds__(256, 8)
k_edgeA(const uv4* __restrict__ hb8, const unsigned short* __restrict__ hb1,
        const uint2* __restrict__ hmA,
        const unsigned char* __restrict__ hmB, const unsigned* __restrict__ binned,
        const int* __restrict__ row_ptr, const unsigned* __restrict__ rpo,
        const float* __restrict__ bond,
        const float* __restrict__ W1l, const float* __restrict__ b1l,
        const float* __restrict__ epsp, uv4* __restrict__ X8,
        unsigned short* __restrict__ X1, float* __restrict__ stats) {
  __shared__ float comb[8 * DD];
  __shared__ float sW1[DD * HH], sb1[HH], ssum[HH], ssq[HH];
  int tid = threadIdx.x;
  for (int i = tid; i < DD * HH; i += 256) sW1[i] = W1l[i];
  if (tid < 8 * DD) {
    int c = tid / DD, d = tid % DD;
    comb[tid] = bond[(0 * 6 + (c & 1)) * DD + d] +
                bond[(1 * 6 + ((c >> 1) & 1)) * DD + d] +
                bond[(2 * 6 + ((c >> 2) & 1)) * DD + d];
  }
  if (tid < HH) { sb1[tid] = b1l[tid]; ssum[tid] = 0.f; ssq[tid] = 0.f; }
  __syncthreads();

  int b = blockIdx.x;
  int nA = b * NPB + tid;
  int nB = nA + 256;
  int ea0 = row_ptr[nA];
  int eb0 = row_ptr[nB];
  unsigned roA = rpo[nA], roB = rpo[nB];
  float acc0[DD] = {0.f,0.f,0.f,0.f,0.f,0.f,0.f,0.f,0.f};
  float acc1[DD] = {0.f,0.f,0.f,0.f,0.f,0.f,0.f,0.f,0.f};

  int pA = ea0, pB = eb0;
#pragma unroll
  for (int q = 0; q < 4; ++q) {
    int eA = ea0 + (int)((roA >> (q * 8)) & 255u);
    int eB = eb0 + (int)((roB >> (q * 8)) & 255u);
    accumNode(binned, pA, eA, hmA, hmB, comb, acc0);
    accumNode(binned, pB, eB, hmA, hmB, comb, acc1);
    pA = eA;
    pB = eB;
    __syncthreads();
  }

  float eps1 = 1.0f + epsp[0];
  float z0[DD], z1[DD];
  {
    float hi[DD];
    unpack9(hb8, hb1, (size_t)nA, hi);
#pragma unroll
    for (int d = 0; d < DD; ++d) z0[d] = eps1 * hi[d] + acc0[d];
    pack9(X8, X1, (size_t)nA, z0);
  }
  {
    float hi[DD];
    unpack9(hb8, hb1, (size_t)nB, hi);
#pragma unroll
    for (int d = 0; d < DD; ++d) z1[d] = eps1 * hi[d] + acc1[d];
    pack9(X8, X1, (size_t)nB, z1);
  }
  int lane0 = ((tid & 63) == 0);
#pragma unroll
  for (int j = 0; j < HH; ++j) {
    float a0 = sb1[j], a1 = sb1[j];
#pragma unroll
    for (int d = 0; d < DD; ++d) {
      a0 += z0[d] * sW1[d * HH + j];
      a1 += z1[d] * sW1[d * HH + j];
    }
    float rs = waveReduce(a0 + a1);
    float rq = waveReduce(a0 * a0 + a1 * a1);
    if (lane0) { atomicAdd(&ssum[j], rs); atomicAdd(&ssq[j], rq); }
  }
  __syncthreads();
  int copy = (b & 63) * 64;
  if (tid < HH) {
    atomicAdd(&stats[copy + NSUM1 + tid], ssum[tid]);
    atomicAdd(&stats[copy + NSQ1 + tid], ssq[tid]);
  }
}

// in-place X (packed bf16): z2 = relu(bn1(z@W1+b1)) @ W2 + b2;  BN2 stats (spread)
__global__ void __launch_bounds__(256)
k_partB(uv4* __restrict__ X8, unsigned short* __restrict__ X1,
        const float* __restrict__ W1l, const float* __restrict__ b1l,
        const float* __restrict__ g1, const float* __restrict__ be1,
        const float* __restrict__ W2l, const float* __restrict__ b2l,
        float* __restrict__ stats) {
  __shared__ float sW1[DD * HH], sW2[HH * DD], sb1[HH], sb2[DD];
  __shared__ float sc1[HH], sh1[HH], ssum[DD], ssq[DD];
  int tid = threadIdx.x;
  for (int i = tid; i < DD * HH; i += 256) sW1[i] = W1l[i];
  for (int i = tid; i < HH * DD; i += 256) sW2[i] = W2l[i];
  if (tid < HH) {
    float s = 0.f, q = 0.f;
#pragma unroll
    for (int c = 0; c < 64; ++c) {
      s += stats[c * 64 + NSUM1 + tid];
      q += stats[c * 64 + NSQ1 + tid];
    }
    float mean = s * (1.0f / NN);
    float var = q * (1.0f / NN) - mean * mean;
    float sc = g1[tid] * rsqrtf(var + BN_EPS);
    sc1[tid] = sc;
    sh1[tid] = be1[tid] - mean * sc;
    sb1[tid] = b1l[tid];
  }
  if (tid < DD) { sb2[tid] = b2l[tid]; ssum[tid] = 0.f; ssq[tid] = 0.f; }
  __syncthreads();
  size_t n = (size_t)blockIdx.x * 256 + tid;
  float z[DD];
  unpack9(X8, X1, n, z);
  float t[HH];
#pragma unroll
  for (int j = 0; j < HH; ++j) {
    float a = sb1[j];
#pragma unroll
    for (int d = 0; d < DD; ++d) a += z[d] * sW1[d * HH + j];
    a = a * sc1[j] + sh1[j];
    t[j] = a > 0.f ? a : 0.f;
  }
  float z2[DD];
  int lane0 = ((tid & 63) == 0);
#pragma unroll
  for (int d = 0; d < DD; ++d) {
    float a = sb2[d];
#pragma unroll
    for (int j = 0; j < HH; ++j) a += t[j] * sW2[j * DD + d];
    z2[d] = a;
    float rs = waveReduce(a);
    float rq = waveReduce(a * a);
    if (lane0) { atomicAdd(&ssum[d], rs); atomicAdd(&ssq[d], rq); }
  }
  pack9(X8, X1, n, z2);
  __syncthreads();
  int copy = ((int)blockIdx.x & 63) * 64;
  if (tid < DD) {
    atomicAdd(&stats[copy + NSUM2 + tid], ssum[tid]);
    atomicAdd(&stats[copy + NSQ2 + tid], ssq[tid]);
  }
}

// h_new = bn2(z2)[relu] + h_in; vn add + packed h + mirrors; last: spread out-sums
__global__ void __launch_bounds__(256)
k_partC(const uv4* __restrict__ X8, const unsigned short* __restrict__ X1,
        uv4* __restrict__ hb8, unsigned short* __restrict__ hb1,
        uint2* __restrict__ hmA, unsigned char* __restrict__ hmB,
        float* __restrict__ stats, const float* __restrict__ g2,
        const float* __restrict__ be2, const int* __restrict__ batch,
        const float* __restrict__ vn_next, float* __restrict__ vnsum_out,
        int do_relu) {
  __shared__ float sc[DD], sh[DD], ssum[DD];
  int tid = threadIdx.x;
  if (tid < DD) {
    float s = 0.f, q = 0.f;
#pragma unroll
    for (int c = 0; c < 64; ++c) {
      s += stats[c * 64 + NSUM2 + tid];
      q += stats[c * 64 + NSQ2 + tid];
    }
    float mean = s * (1.0f / NN);
    float var = q * (1.0f / NN) - mean * mean;
    float sg = g2[tid] * rsqrtf(var + BN_EPS);
    sc[tid] = sg;
    sh[tid] = be2[tid] - mean * sg;
    ssum[tid] = 0.f;
  }
  __syncthreads();
  size_t n = (size_t)blockIdx.x * 256 + tid;
  float zv[DD];
  unpack9(X8, X1, n, zv);
  float hi[DD];
  unpack9(hb8, hb1, n, hi);
  float hv[DD];
#pragma unroll
  for (int d = 0; d < DD; ++d) {
    float z = zv[d] * sc[d] + sh[d];
    if (do_relu) z = z > 0.f ? z : 0.f;
    hv[d] = z + hi[d];
  }
  if (vn_next != nullptr) {
    int g = batch[n];
#pragma unroll
    for (int d = 0; d < DD; ++d) hv[d] += vn_next[(size_t)g * DD + d];
    pack9(hb8, hb1, n, hv);
    writeMirror(hmA, hmB, n, hv);
    if (vnsum_out != nullptr) {
      int lane = tid & 63;
      float s[DD];
#pragma unroll
      for (int d = 0; d < DD; ++d) s[d] = hv[d];
#pragma unroll
      for (int st = 1; st < 64; st <<= 1) {
        int gu = __shfl_up(g, st, 64);
        bool ok = (lane >= st) && (gu == g);
#pragma unroll
        for (int d = 0; d < DD; ++d) {
          float vu = __shfl_up(s[d], st, 64);
          if (ok) s[d] += vu;
        }
      }
      int gn = __shfl_down(g, 1, 64);
      if ((lane == 63) || (gn != g)) {
#pragma unroll
        for (int d = 0; d < DD; ++d) atomicAdd(&vnsum_out[(size_t)g * DD + d], s[d]);
      }
    }
  } else {
    int lane0 = ((tid & 63) == 0);
#pragma unroll
    for (int d = 0; d < DD; ++d) {
      float r = waveReduce(hv[d]);
      if (lane0) atomicAdd(&ssum[d], r);
    }
    __syncthreads();
    int copy = ((int)blockIdx.x & 63) * 64;
    if (tid < DD) atomicAdd(&stats[copy + OUTS + tid], ssum[tid]);
  }
}

// reduce spread out-sums -> d_out
__global__ void k_out(const float* __restrict__ stats, float* __restrict__ out) {
  int tid = threadIdx.x;
  if (tid < DD) {
    float s = 0.f;
#pragma unroll
    for (int c = 0; c < 64; ++c) s += stats[c * 64 + OUTS + tid];
    out[tid] = s;
  }
}

// ---------------- fused virtual-node MLP (grid-sync via spin barrier) ----------------
// VNB=128 blocks <= CU count -> all co-resident; barrier slots zeroed by the
// per-layer stats memset; gen is read BEFORE arrival so no block can spin on a
// post-bump value; post-barrier stat reads use device-scope RMW (atomicAdd 0).

__device__ __forceinline__ void gridBar(int* cnt, int* gen) {
  __syncthreads();
  if (threadIdx.x == 0) {
    __threadfence();
    int g = atomicAdd(gen, 0);
    __threadfence();
    int t = atomicAdd(cnt, 1 | (g >> 31));   // data-dep: g read precedes arrival
    if (t == VNB - 1) {
      atomicAdd(gen, 1);
    } else {
      while (atomicAdd(gen, 0) == g) __builtin_amdgcn_s_sleep(8);
    }
    __threadfence();
  }
  __syncthreads();
}

__global__ void __launch_bounds__(256)
k_vn(const float* __restrict__ vnsum, float* __restrict__ vn,
     const float* __restrict__ W1l, const float* __restrict__ b1l,
     const float* __restrict__ g1, const float* __restrict__ be1,
     const float* __restrict__ W2l, const float* __restrict__ b2l,
     const float* __restrict__ g2, const float* __restrict__ be2,
     float* __restrict__ stats) {
  __shared__ float sW1[DD * HH], sW2[HH * DD], sb1[HH], sb2[DD];
  __shared__ float ssum[HH], ssq[HH], sc1[HH], sh1[HH];
  int tid = threadIdx.x;
  int* bar = (int*)(stats + BARS);
  for (int i = tid; i < DD * HH; i += 256) { sW1[i] = W1l[i]; sW2[i] = W2l[i]; }
  if (tid < HH) { sb1[tid] = b1l[tid]; ssum[tid] = 0.f; ssq[tid] = 0.f; }
  if (tid < DD) sb2[tid] = b2l[tid];
  __syncthreads();
  size_t g = (size_t)blockIdx.x * 256 + tid;
  float r[DD];
#pragma unroll
  for (int d = 0; d < DD; ++d) r[d] = vnsum[g * DD + d] + vn[g * DD + d];
  int lane0 = ((tid & 63) == 0);
  float a1[HH];
#pragma unroll
  for (int j = 0; j < HH; ++j) {
    float a = sb1[j];
#pragma unroll
    for (int d = 0; d < DD; ++d) a += r[d] * sW1[d * HH + j];
    a1[j] = a;
    float rs = waveReduce(a);
    float rq = waveReduce(a * a);
    if (lane0) { atomicAdd(&ssum[j], rs); atomicAdd(&ssq[j], rq); }
  }
  __syncthreads();
  if (tid < HH) {
    atomicAdd(&stats[VSUM1 + tid], ssum[tid]);
    atomicAdd(&stats[VSQ1 + tid], ssq[tid]);
  }
  gridBar(&bar[0], &bar[1]);
  if (tid < HH) {
    float s = atomicAdd(&stats[VSUM1 + tid], 0.0f);   // device-coherent read
    float q = atomicAdd(&stats[VSQ1 + tid], 0.0f);
    float mean = s * (1.0f / NG);
    float var = q * (1.0f / NG) - mean * mean;
    float sc = g1[tid] * rsqrtf(var + BN_EPS);
    sc1[tid] = sc;
    sh1[tid] = be1[tid] - mean * sc;
  }
  if (tid < DD) { ssum[tid] = 0.f; ssq[tid] = 0.f; }
  __syncthreads();
  float t[HH];
#pragma unroll
  for (int j = 0; j < HH; ++j) {
    float a = a1[j] * sc1[j] + sh1[j];
    t[j] = a > 0.f ? a : 0.f;
  }
  float z2[DD];
#pragma unroll
  for (int d = 0; d < DD; ++d) {
    float a = sb2[d];
#pragma unroll
    for (int j = 0; j < HH; ++j) a += t[j] * sW2[j * DD + d];
    z2[d] = a;
    float rs = waveReduce(a);
    float rq = waveReduce(a * a);
    if (lane0) { atomicAdd(&ssum[d], rs); atomicAdd(&ssq[d], rq); }
  }
  __syncthreads();
  if (tid < DD) {
    atomicAdd(&stats[VSUM2 + tid], ssum[tid]);
    atomicAdd(&stats[VSQ2 + tid], ssq[tid]);
  }
  gridBar(&bar[2], &bar[3]);
  if (tid < DD) {
    float s = atomicAdd(&stats[VSUM2 + tid], 0.0f);
    float q = atomicAdd(&stats[VSQ2 + tid], 0.0f);
    float mean = s * (1.0f / NG);
    float var = q * (1.0f / NG) - mean * mean;
    float sc = g2[tid] * rsqrtf(var + BN_EPS);
    sc1[tid] = sc;                 // reuse as sc2/sh2
    sh1[tid] = be2[tid] - mean * sc;
  }
  __syncthreads();
#pragma unroll
  for (int d = 0; d < DD; ++d) {
    float v = z2[d] * sc1[d] + sh1[d];
    v = v > 0.f ? v : 0.f;
    vn[g * DD + d] += v;
  }
}

extern "C" void kernel_launch(void* const* d_in, const int* in_sizes, int n_in,
                              void* d_out, int out_size, void* d_ws, size_t ws_size,
                              hipStream_t stream) {
  const float* atom_emb = (const float*)d_in[0];
  const float* bond_emb = (const float*)d_in[1];
  const float* eps_gin  = (const float*)d_in[2];
  const float* W1   = (const float*)d_in[3];
  const float* b1   = (const float*)d_in[4];
  const float* bn1_g = (const float*)d_in[5];
  const float* bn1_b = (const float*)d_in[6];
  const float* W2   = (const float*)d_in[7];
  const float* b2   = (const float*)d_in[8];
  const float* bno_g = (const float*)d_in[9];
  const float* bno_b = (const float*)d_in[10];
  const float* vnW1 = (const float*)d_in[11];
  const float* vnb1 = (const float*)d_in[12];
  const float* vnbn1_g = (const float*)d_in[13];
  const float* vnbn1_b = (const float*)d_in[14];
  const float* vnW2 = (const float*)d_in[15];
  const float* vnb2 = (const float*)d_in[16];
  const float* vnbn2_g = (const float*)d_in[17];
  const float* vnbn2_b = (const float*)d_in[18];
  const int* x          = (const int*)d_in[19];
  const int* edge_index = (const int*)d_in[20];
  const int* edge_attr  = (const int*)d_in[21];
  const int* batch      = (const int*)d_in[22];
  float* out = (float*)d_out;

  // workspace layout — ~115 MB.
  // Region 0: union of transient coarse (NE uint2, 67.1 MB) + cnt_pad + blkcnt
  // with persistent hb8/hb1/X8/X1 packed bf16 node streams (37.75 MB, live
  // from k_atom which runs after all transient users are done).
  char* base = (char*)d_ws;
  uv4* hb8 = (uv4*)base;                                 // NN uint4
  unsigned short* hb1 = (unsigned short*)(hb8 + (size_t)NN);
  uv4* X8 = (uv4*)(hb1 + (size_t)NN);                    // NN uint4
  unsigned short* X1 = (unsigned short*)(X8 + (size_t)NN);
  uint2* coarse = (uint2*)base;                          // NE uint2 (transient)
  int* cnt_pad  = (int*)(coarse + (size_t)NE);           // NB*16 (transient)
  int* blkcnt   = cnt_pad + (size_t)NB * 16;             // NGRP*P1B (transient)
  char* pers = (char*)(blkcnt + (size_t)NGRP * P1B);
  uint2* hmA   = (uint2*)pers;                           // NN uint2 (8 MB)
  unsigned char* hmB = (unsigned char*)(hmA + (size_t)NN);  // NN bytes (1 MB)
  unsigned* binned = (unsigned*)(hmB + (size_t)NN);      // NE u32 (33.5 MB)
  float* vn    = (float*)(binned + (size_t)NE);          // NG*DD
  float* vnsum = vn + (size_t)NG * DD;                   // NG*DD
  float* stats = vnsum + (size_t)NG * DD;                // STATS_FLOATS
  int* bucket_base   = (int*)(stats + STATS_FLOATS);     // NB+1
  int* bucket_cursor = bucket_base + NB + 1;             // NB
  int* row_ptr       = bucket_cursor + NB;               // NN+1 (4 MB)
  unsigned* rpo      = (unsigned*)(row_ptr + NN + 1);    // NN u32 (4 MB)

  // ---- one-time binning (deterministic two-pass) ----
  (void)hipMemsetAsync(cnt_pad, 0, (size_t)NB * 16 * sizeof(int), stream);
  k_counthist<<<P1B, 1024, 0, stream>>>(edge_index, cnt_pad, blkcnt);
  k_scan<<<1, 256, 0, stream>>>(cnt_pad, bucket_base, bucket_cursor);
  k_scanG<<<NGRP, 256, 0, stream>>>(blkcnt, bucket_base);
  k_p1<<<P1B, 1024, 0, stream>>>(edge_index, edge_attr, blkcnt, coarse);
  k_p2<<<NGRP * P2SUB, 256, 0, stream>>>(coarse, bucket_base, bucket_cursor, binned);
  k_p3<<<NB, 256, 0, stream>>>(binned, bucket_base, row_ptr, rpo);

  (void)hipMemsetAsync(vn, 0, (size_t)2 * NG * DD * sizeof(float), stream);
  k_atom<<<NN / 256, 256, 0, stream>>>(atom_emb, x, batch, hb8, hb1, hmA, hmB, vnsum);

  for (int l = 0; l < 3; ++l) {
    int has_vn = (l < 2);
    (void)hipMemsetAsync(stats, 0, STATS_FLOATS * sizeof(float), stream);
    if (has_vn) {
      k_vn<<<VNB, 256, 0, stream>>>(vnsum, vn,
                                    vnW1 + (size_t)l * DD * HH, vnb1 + (size_t)l * HH,
                                    vnbn1_g + (size_t)l * HH, vnbn1_b + (size_t)l * HH,
                                    vnW2 + (size_t)l * HH * DD, vnb2 + (size_t)l * DD,
                                    vnbn2_g + (size_t)l * DD, vnbn2_b + (size_t)l * DD,
                                    stats);
    }
    k_edgeA<<<NB, 256, 0, stream>>>(hb8, hb1, hmA, hmB, binned, row_ptr, rpo,
                                    bond_emb + (size_t)l * 3 * 6 * DD,
                                    W1 + (size_t)l * DD * HH, b1 + (size_t)l * HH,
                                    eps_gin + l, X8, X1, stats);
    k_partB<<<NN / 256, 256, 0, stream>>>(X8, X1, W1 + (size_t)l * DD * HH,
                                          b1 + (size_t)l * HH,
                                          bn1_g + (size_t)l * HH, bn1_b + (size_t)l * HH,
                                          W2 + (size_t)l * HH * DD, b2 + (size_t)l * DD,
                                          stats);
    if (l == 0)
      (void)hipMemsetAsync(vnsum, 0, (size_t)NG * DD * sizeof(float), stream);
    k_partC<<<NN / 256, 256, 0, stream>>>(X8, X1, hb8, hb1, hmA, hmB, stats,
                                          bno_g + (size_t)l * DD, bno_b + (size_t)l * DD,
                                          batch,
                                          has_vn ? vn : nullptr,
                                          (l == 0) ? vnsum : nullptr,
                                          has_vn ? 1 : 0);
  }
  k_out<<<1, 64, 0, stream>>>(stats, out);
}

// Round 13
// 1216.858 us; speedup vs baseline: 1.1176x; 1.0389x over previous
//
#include <hip/hip_runtime.h>
#include <hip/hip_fp8.h>

#define NN 1048576   // nodes (= 2^20, src fits 20 bits)
#define NE 8388608   // edges
#define NG 32768     // graphs
#define DD 9         // emb dim
#define HH 18        // hidden
#define BN_EPS 1e-5f

#define NPB 512      // nodes per dst bucket
#define NB  2048     // dst buckets
#define NGRP 64      // coarse dst-groups
#define P1B 512      // k_p1 / counthist blocks
#define P3MAX 5120   // max edges per bucket staged in k_p3 (Poisson(4096), safe)
#define P3KEYS 2048  // 512 nodes x 4 src-quartiles

// spread stats: 64 copies x 64 chans, 3 per-layer copies (zeroed once upfront)
#define NSUM1 0      // 18
#define NSQ1  18     // 18
#define NSUM2 36     // 9
#define NSQ2  45     // 9
#define OUTS  54     // 9
#define VBASE 4096   // VN stats (single copy)
#define VSUM1 (VBASE+0)
#define VSQ1  (VBASE+18)
#define VSUM2 (VBASE+36)
#define VSQ2  (VBASE+45)
#define STATS_FLOATS 4224

typedef float fv4 __attribute__((ext_vector_type(4)));
typedef unsigned uv4 __attribute__((ext_vector_type(4)));

__device__ __forceinline__ float waveReduce(float v) {
#pragma unroll
  for (int off = 32; off > 0; off >>= 1) v += __shfl_down(v, off, 64);
  return v;
}
__device__ __forceinline__ unsigned f8enc(float f) {
  __hip_fp8_e4m3 v(f);
  return (unsigned)v.__x;
}
__device__ __forceinline__ float f8dec(unsigned b) {
  __hip_fp8_e4m3 v;
  v.__x = (__hip_fp8_storage_t)b;
  return (float)v;
}
// bf16 round-to-nearest-even pack/unpack
__device__ __forceinline__ unsigned bf16r(float x) {
  unsigned u = __float_as_uint(x);
  unsigned r = u + 0x7FFFu + ((u >> 16) & 1u);
  return r >> 16;
}
__device__ __forceinline__ unsigned pk2(float a, float b) {
  return bf16r(a) | (bf16r(b) << 16);
}
__device__ __forceinline__ float lo16(unsigned u) { return __uint_as_float(u << 16); }
__device__ __forceinline__ float hi16(unsigned u) { return __uint_as_float(u & 0xFFFF0000u); }

__device__ __forceinline__ void pack9(uv4* __restrict__ b8, unsigned short* __restrict__ b1,
                                      size_t n, const float* v) {
  uv4 p;
  p.x = pk2(v[0], v[1]); p.y = pk2(v[2], v[3]);
  p.z = pk2(v[4], v[5]); p.w = pk2(v[6], v[7]);
  __builtin_nontemporal_store(p, &b8[n]);
  __builtin_nontemporal_store((unsigned short)bf16r(v[8]), &b1[n]);
}
__device__ __forceinline__ void unpack9(const uv4* __restrict__ b8,
                                        const unsigned short* __restrict__ b1,
                                        size_t n, float* v) {
  uv4 P = __builtin_nontemporal_load(&b8[n]);
  unsigned short s = b1[n];
  v[0] = lo16(P.x); v[1] = hi16(P.x); v[2] = lo16(P.y); v[3] = hi16(P.y);
  v[4] = lo16(P.z); v[5] = hi16(P.z); v[6] = lo16(P.w); v[7] = hi16(P.w);
  v[8] = __uint_as_float((unsigned)s << 16);
}

// ---------------- binning (once per launch) ----------------
// PROVEN two-pass deterministic counting-sort (round-10 structure).
// counthist/scan/scanG -> deterministic per-(block,group) bases; p1 scatters
// 8B records into 64 coarse group streams; p2 -> 32 fine buckets per group
// (LDS-staged, coalesced); p3 sorts each bucket by (local_dst, src_quartile)
// and emits CSR row_ptr + byte-packed quartile offsets (rpo).

__global__ void __launch_bounds__(1024)
k_counthist(const int* __restrict__ ei, int* __restrict__ cnt_pad,
            int* __restrict__ blkcnt) {
  __shared__ int hist[NB];   // 8 KB
  int tid = threadIdx.x;
  for (int i = tid; i < NB; i += 1024) hist[i] = 0;
  __syncthreads();
  const int CH = NE / P1B;   // 16384
  int base = blockIdx.x * CH;
  for (int i = tid; i < CH; i += 1024)
    atomicAdd(&hist[ei[NE + base + i] >> 9], 1);
  __syncthreads();
  for (int i = tid; i < NB; i += 1024)
    if (hist[i]) atomicAdd(&cnt_pad[i * 16], hist[i]);
  if (tid < NGRP) {
    int s = 0;
#pragma unroll
    for (int k = 0; k < 32; ++k) s += hist[tid * 32 + k];
    blkcnt[tid * P1B + blockIdx.x] = s;
  }
}

__global__ void k_scan(const int* __restrict__ cnt_pad, int* __restrict__ bucket_base,
                       int* __restrict__ bucket_cursor) {
  __shared__ int tsum[256];
  int tid = threadIdx.x;
  int c[8];
  int run = 0;
#pragma unroll
  for (int k = 0; k < 8; ++k) { c[k] = cnt_pad[(tid * 8 + k) * 16]; run += c[k]; }
  tsum[tid] = run;
  __syncthreads();
  for (int off = 1; off < 256; off <<= 1) {
    int v = (tid >= off) ? tsum[tid - off] : 0;
    __syncthreads();
    tsum[tid] += v;
    __syncthreads();
  }
  int excl = tsum[tid] - run;
#pragma unroll
  for (int k = 0; k < 8; ++k) {
    bucket_base[tid * 8 + k] = excl;
    bucket_cursor[tid * 8 + k] = excl;
    excl += c[k];
  }
  if (tid == 255) bucket_base[NB] = tsum[255];
}

// per-group exclusive scan of the P1B block counts -> write bases (in place)
__global__ void k_scanG(int* __restrict__ blkcnt, const int* __restrict__ bucket_base) {
  __shared__ int tsum[256];
  int tid = threadIdx.x;
  int g = blockIdx.x;
  int c0 = blkcnt[g * P1B + 2 * tid], c1 = blkcnt[g * P1B + 2 * tid + 1];
  int run = c0 + c1;
  tsum[tid] = run;
  __syncthreads();
  for (int off = 1; off < 256; off <<= 1) {
    int v = (tid >= off) ? tsum[tid - off] : 0;
    __syncthreads();
    tsum[tid] += v;
    __syncthreads();
  }
  int excl = tsum[tid] - run + bucket_base[g << 5];
  blkcnt[g * P1B + 2 * tid] = excl;
  blkcnt[g * P1B + 2 * tid + 1] = excl + c0;
}

__global__ void __launch_bounds__(1024)
k_p1(const int* __restrict__ ei, const int* __restrict__ ea,
     const int* __restrict__ blkcnt, uint2* __restrict__ coarse) {
  __shared__ int lcnt[NGRP];
  __shared__ int lbase[NGRP];
  int tid = threadIdx.x;
  if (tid < NGRP) { lcnt[tid] = 0; lbase[tid] = blkcnt[tid * P1B + blockIdx.x]; }
  __syncthreads();
  const int CH = NE / P1B;   // 16384
  int base = blockIdx.x * CH;
  for (int k = 0; k < CH / 1024; ++k) {
    int e = base + k * 1024 + tid;
    int s = ei[e];
    int d = ei[NE + e];
    unsigned at = (unsigned)((ea[(size_t)e * 3 + 0] & 1) |
                             ((ea[(size_t)e * 3 + 1] & 1) << 1) |
                             ((ea[(size_t)e * 3 + 2] & 1) << 2));
    int g = d >> 14;
    int pos = atomicAdd(&lcnt[g], 1);
    coarse[lbase[g] + pos] = make_uint2((unsigned)s | (at << 20), (unsigned)d);
  }
}

#define P2K 48
#define P2SUB 32
__global__ void __launch_bounds__(256)
k_p2(const uint2* __restrict__ coarse, const int* __restrict__ bucket_base,
     int* __restrict__ bucket_cursor, unsigned* __restrict__ binned) {
  __shared__ unsigned stage[32 * P2K];
  __shared__ int scnt[32], gbase[32];
  int tid = threadIdx.x;
  int g = blockIdx.x >> 5;
  int sub = blockIdx.x & 31;
  int s0 = bucket_base[g << 5];
  int s1 = bucket_base[(g + 1) << 5];
  int len = s1 - s0;
  int chunk = (len + P2SUB - 1) >> 5;
  int my0 = s0 + sub * chunk;
  int my1 = min(my0 + chunk, s1);
  if (tid < 32) scnt[tid] = 0;
  __syncthreads();
  for (int b0 = my0; b0 < my1; b0 += 1024) {
#pragma unroll
    for (int k = 0; k < 4; ++k) {
      int i = b0 + k * 256 + tid;
      if (i < my1) {
        uint2 rec = coarse[i];
        unsigned s = rec.x & 0xFFFFFu;
        unsigned at = rec.x >> 20;
        unsigned d = rec.y;
        int bt = (int)((d >> 9) & 31u);
        unsigned o = s | ((d & 511u) << 20) | (at << 29);
        int pos = atomicAdd(&scnt[bt], 1);
        if (pos < P2K) stage[bt * P2K + pos] = o;
        else binned[atomicAdd(&bucket_cursor[(g << 5) | bt], 1)] = o;
      }
    }
    __syncthreads();
    {
      int bt = tid >> 3, j = tid & 7;
      int cnt = min(scnt[bt], P2K);
      if (j == 0) gbase[bt] = cnt ? atomicAdd(&bucket_cursor[(g << 5) | bt], cnt) : 0;
      __syncthreads();
      for (int i = j; i < cnt; i += 8) binned[gbase[bt] + i] = stage[bt * P2K + i];
    }
    __syncthreads();
    if (tid < 32) scnt[tid] = 0;
    __syncthreads();
  }
}

// counting-sort each dst bucket by (local_dst<<2 | src_quartile); in-place;
// emits CSR row_ptr + byte-packed per-node cumulative quartile offsets (rpo).
// Final record: src (bits 0-19) | attr (bits 20-22).
__global__ void __launch_bounds__(256)
k_p3(unsigned* __restrict__ binned, const int* __restrict__ bucket_base,
     int* __restrict__ row_ptr, unsigned* __restrict__ rpo) {
  __shared__ int cnt[P3KEYS];       // 8 KB
  __shared__ int tsum[256];
  __shared__ unsigned stage[P3MAX]; // 20 KB
  int tid = threadIdx.x;
  int b = blockIdx.x;
  int s0 = bucket_base[b], s1 = bucket_base[b + 1];
  int len = s1 - s0;
  for (int i = tid; i < P3KEYS; i += 256) cnt[i] = 0;
  __syncthreads();
  for (int i = tid; i < len; i += 256) {
    unsigned rec = binned[s0 + i];
    int key = (int)((((rec >> 20) & 511u) << 2) | ((rec & 0xFFFFFu) >> 18));
    atomicAdd(&cnt[key], 1);
  }
  __syncthreads();
  int c[8];
  int run = 0;
#pragma unroll
  for (int k = 0; k < 8; ++k) { c[k] = cnt[tid * 8 + k]; run += c[k]; }
  tsum[tid] = run;
  __syncthreads();
  for (int off = 1; off < 256; off <<= 1) {
    int v = (tid >= off) ? tsum[tid - off] : 0;
    __syncthreads();
    tsum[tid] += v;
    __syncthreads();
  }
  int excl = tsum[tid] - run;
  int sum4 = c[0] + c[1] + c[2] + c[3];
  // thread tid owns local nodes 2*tid (keys 0-3) and 2*tid+1 (keys 4-7)
  row_ptr[b * NPB + 2 * tid] = s0 + excl;
  row_ptr[b * NPB + 2 * tid + 1] = s0 + excl + sum4;
  if (b == NB - 1 && tid == 255) row_ptr[NN] = s0 + excl + run;  // == NE
  {  // cumulative-inclusive quartile offsets, byte-packed (degree <= ~45 << 255)
    unsigned roA = 0, roB = 0;
    int rA = 0, rB = 0;
#pragma unroll
    for (int k = 0; k < 4; ++k) {
      rA += c[k];      roA |= (unsigned)rA << (k * 8);
      rB += c[4 + k];  roB |= (unsigned)rB << (k * 8);
    }
    rpo[(size_t)b * NPB + 2 * tid] = roA;
    rpo[(size_t)b * NPB + 2 * tid + 1] = roB;
  }
  int e = excl;
#pragma unroll
  for (int k = 0; k < 8; ++k) { cnt[tid * 8 + k] = e; e += c[k]; }
  __syncthreads();
  for (int i = tid; i < len; i += 256) {
    unsigned rec = binned[s0 + i];
    int key = (int)((((rec >> 20) & 511u) << 2) | ((rec & 0xFFFFFu) >> 18));
    int pos = atomicAdd(&cnt[key], 1);
    stage[pos] = (rec & 0xFFFFFu) | ((rec >> 29) << 20);
  }
  __syncthreads();
  for (int i = tid; i < len; i += 256) binned[s0 + i] = stage[i];
}

// ---------------- per-layer kernels ----------------

__device__ __forceinline__ void writeMirror(uint2* __restrict__ hmA,
                                            unsigned char* __restrict__ hmB,
                                            size_t n, const float* hv) {
  uint2 q;
  q.x = f8enc(hv[0]) | (f8enc(hv[1]) << 8) | (f8enc(hv[2]) << 16) | (f8enc(hv[3]) << 24);
  q.y = f8enc(hv[4]) | (f8enc(hv[5]) << 8) | (f8enc(hv[6]) << 16) | (f8enc(hv[7]) << 24);
  hmA[n] = q;
  hmB[n] = (unsigned char)f8enc(hv[8]);
}

// h_in(0) = atom embed sum; packed bf16 h; mirrors; vnsum0 = segsum
__global__ void k_atom(const float* __restrict__ atom_emb, const int* __restrict__ x,
                       const int* __restrict__ batch,
                       uv4* __restrict__ hb8, unsigned short* __restrict__ hb1,
                       uint2* __restrict__ hmA, unsigned char* __restrict__ hmB,
                       float* __restrict__ vnsum) {
  int n = blockIdx.x * 256 + threadIdx.x;
  int xi[9];
#pragma unroll
  for (int f = 0; f < 9; ++f) xi[f] = x[(size_t)n * 9 + f];
  float acc[DD] = {0.f,0.f,0.f,0.f,0.f,0.f,0.f,0.f,0.f};
#pragma unroll
  for (int f = 0; f < 9; ++f) {
    const float* row = atom_emb + ((size_t)f * 119 + xi[f]) * DD;
#pragma unroll
    for (int d = 0; d < DD; ++d) acc[d] += row[d];
  }
  pack9(hb8, hb1, (size_t)n, acc);
  writeMirror(hmA, hmB, (size_t)n, acc);
  int g = batch[n];
  int lane = threadIdx.x & 63;
  float s[DD];
#pragma unroll
  for (int d = 0; d < DD; ++d) s[d] = acc[d];
#pragma unroll
  for (int st = 1; st < 64; st <<= 1) {
    int gu = __shfl_up(g, st, 64);
    bool ok = (lane >= st) && (gu == g);
#pragma unroll
    for (int d = 0; d < DD; ++d) {
      float vu = __shfl_up(s[d], st, 64);
      if (ok) s[d] += vu;
    }
  }
  int gn = __shfl_down(g, 1, 64);
  if ((lane == 63) || (gn != g)) {
#pragma unroll
    for (int d = 0; d < DD; ++d) atomicAdd(&vnsum[(size_t)g * DD + d], s[d]);
  }
}

__device__ __forceinline__ void edgeDecodeAcc(unsigned r, uint2 q, unsigned db,
                                              const float* __restrict__ comb,
                                              float* __restrict__ acc) {
  const float* cb = comb + (r >> 20) * DD;
  float hv[DD] = {f8dec(q.x & 255u), f8dec((q.x >> 8) & 255u),
                  f8dec((q.x >> 16) & 255u), f8dec(q.x >> 24),
                  f8dec(q.y & 255u), f8dec((q.y >> 8) & 255u),
                  f8dec((q.y >> 16) & 255u), f8dec(q.y >> 24),
                  f8dec(db)};
#pragma unroll
  for (int d = 0; d < DD; ++d) {
    float m = hv[d] + cb[d];
    m = m > 0.f ? m : 0.f;
    acc[d] += m;
  }
}

// counted 4-deep pipelined sweep over [e0,e1)
__device__ __forceinline__ void accumNode(const unsigned* __restrict__ binned,
                                          int e0, int e1,
                                          const uint2* __restrict__ hmA,
                                          const unsigned char* __restrict__ hmB,
                                          const float* __restrict__ comb,
                                          float* __restrict__ acc) {
  int i = e0;
  for (; i + 4 <= e1; i += 4) {
    unsigned r0 = binned[i], r1 = binned[i + 1], r2 = binned[i + 2], r3 = binned[i + 3];
    uint2 q0 = hmA[r0 & 0xFFFFFu];
    uint2 q1 = hmA[r1 & 0xFFFFFu];
    uint2 q2 = hmA[r2 & 0xFFFFFu];
    uint2 q3 = hmA[r3 & 0xFFFFFu];
    unsigned char d0 = hmB[r0 & 0xFFFFFu];
    unsigned char d1 = hmB[r1 & 0xFFFFFu];
    unsigned char d2 = hmB[r2 & 0xFFFFFu];
    unsigned char d3 = hmB[r3 & 0xFFFFFu];
    edgeDecodeAcc(r0, q0, d0, comb, acc);
    edgeDecodeAcc(r1, q1, d1, comb, acc);
    edgeDecodeAcc(r2, q2, d2, comb, acc);
    edgeDecodeAcc(r3, q3, d3, comb, acc);
  }
  for (; i < e1; ++i) {
    unsigned r = binned[i];
    uint2 q = hmA[r & 0xFFFFFu];
    unsigned char db = hmB[r & 0xFFFFFu];
    edgeDecodeAcc(r, q, db, comb, acc);
  }
}

// Fused: CSR register-aggregate fp8-mirror messages; 4 barrier-paced COUNTED
// src-quartile phases; z=(1+eps)h_in+aggr -> X (packed bf16); BN1 stats (fp32)
__global__ void __launch_bounds__(256, 8)
k_edgeA(const uv4* __restrict__ hb8, const unsigned short* __restrict__ hb1,
        const uint2* __restrict__ hmA,
        const unsigned char* __restrict__ hmB, const unsigned* __restrict__ binned,
        const int* __restrict__ row_ptr, const unsigned* __restrict__ rpo,
        const float* __restrict__ bond,
        const float* __restrict__ W1l, const float* __restrict__ b1l,
        const float* __restrict__ epsp, uv4* __restrict__ X8,
        unsigned short* __restrict__ X1, float* __restrict__ stats) {
  __shared__ float comb[8 * DD];
  __shared__ float sW1[DD * HH], sb1[HH], ssum[HH], ssq[HH];
  int tid = threadIdx.x;
  for (int i = tid; i < DD * HH; i += 256) sW1[i] = W1l[i];
  if (tid < 8 * DD) {
    int c = tid / DD, d = tid % DD;
    comb[tid] = bond[(0 * 6 + (c & 1)) * DD + d] +
                bond[(1 * 6 + ((c >> 1) & 1)) * DD + d] +
                bond[(2 * 6 + ((c >> 2) & 1)) * DD + d];
  }
  if (tid < HH) { sb1[tid] = b1l[tid]; ssum[tid] = 0.f; ssq[tid] = 0.f; }
  __syncthreads();

  int b = blockIdx.x;
  int nA = b * NPB + tid;
  int nB = nA + 256;
  int ea0 = row_ptr[nA];
  int eb0 = row_ptr[nB];
  unsigned roA = rpo[nA], roB = rpo[nB];
  float acc0[DD] = {0.f,0.f,0.f,0.f,0.f,0.f,0.f,0.f,0.f};
  float acc1[DD] = {0.f,0.f,0.f,0.f,0.f,0.f,0.f,0.f,0.f};

  int pA = ea0, pB = eb0;
#pragma unroll
  for (int q = 0; q < 4; ++q) {
    int eA = ea0 + (int)((roA >> (q * 8)) & 255u);
    int eB = eb0 + (int)((roB >> (q * 8)) & 255u);
    accumNode(binned, pA, eA, hmA, hmB, comb, acc0);
    accumNode(binned, pB, eB, hmA, hmB, comb, acc1);
    pA = eA;
    pB = eB;
    __syncthreads();
  }

  float eps1 = 1.0f + epsp[0];
  float z0[DD], z1[DD];
  {
    float hi[DD];
    unpack9(hb8, hb1, (size_t)nA, hi);
#pragma unroll
    for (int d = 0; d < DD; ++d) z0[d] = eps1 * hi[d] + acc0[d];
    pack9(X8, X1, (size_t)nA, z0);
  }
  {
    float hi[DD];
    unpack9(hb8, hb1, (size_t)nB, hi);
#pragma unroll
    for (int d = 0; d < DD; ++d) z1[d] = eps1 * hi[d] + acc1[d];
    pack9(X8, X1, (size_t)nB, z1);
  }
  int lane0 = ((tid & 63) == 0);
#pragma unroll
  for (int j = 0; j < HH; ++j) {
    float a0 = sb1[j], a1 = sb1[j];
#pragma unroll
    for (int d = 0; d < DD; ++d) {
      a0 += z0[d] * sW1[d * HH + j];
      a1 += z1[d] * sW1[d * HH + j];
    }
    float rs = waveReduce(a0 + a1);
    float rq = waveReduce(a0 * a0 + a1 * a1);
    if (lane0) { atomicAdd(&ssum[j], rs); atomicAdd(&ssq[j], rq); }
  }
  __syncthreads();
  int copy = (b & 63) * 64;
  if (tid < HH) {
    atomicAdd(&stats[copy + NSUM1 + tid], ssum[tid]);
    atomicAdd(&stats[copy + NSQ1 + tid], ssq[tid]);
  }
}

// in-place X (packed bf16): z2 = relu(bn1(z@W1+b1)) @ W2 + b2;  BN2 stats (spread)
__global__ void __launch_bounds__(256)
k_partB(uv4* __restrict__ X8, unsigned short* __restrict__ X1,
        const float* __restrict__ W1l, const float* __restrict__ b1l,
        const float* __restrict__ g1, const float* __restrict__ be1,
        const float* __restrict__ W2l, const float* __restrict__ b2l,
        float* __restrict__ stats) {
  __shared__ float sW1[DD * HH], sW2[HH * DD], sb1[HH], sb2[DD];
  __shared__ float sc1[HH], sh1[HH], ssum[DD], ssq[DD];
  int tid = threadIdx.x;
  for (int i = tid; i < DD * HH; i += 256) sW1[i] = W1l[i];
  for (int i = tid; i < HH * DD; i += 256) sW2[i] = W2l[i];
  if (tid < HH) {
    float s = 0.f, q = 0.f;
#pragma unroll
    for (int c = 0; c < 64; ++c) {
      s += stats[c * 64 + NSUM1 + tid];
      q += stats[c * 64 + NSQ1 + tid];
    }
    float mean = s * (1.0f / NN);
    float var = q * (1.0f / NN) - mean * mean;
    float sc = g1[tid] * rsqrtf(var + BN_EPS);
    sc1[tid] = sc;
    sh1[tid] = be1[tid] - mean * sc;
    sb1[tid] = b1l[tid];
  }
  if (tid < DD) { sb2[tid] = b2l[tid]; ssum[tid] = 0.f; ssq[tid] = 0.f; }
  __syncthreads();
  size_t n = (size_t)blockIdx.x * 256 + tid;
  float z[DD];
  unpack9(X8, X1, n, z);
  float t[HH];
#pragma unroll
  for (int j = 0; j < HH; ++j) {
    float a = sb1[j];
#pragma unroll
    for (int d = 0; d < DD; ++d) a += z[d] * sW1[d * HH + j];
    a = a * sc1[j] + sh1[j];
    t[j] = a > 0.f ? a : 0.f;
  }
  float z2[DD];
  int lane0 = ((tid & 63) == 0);
#pragma unroll
  for (int d = 0; d < DD; ++d) {
    float a = sb2[d];
#pragma unroll
    for (int j = 0; j < HH; ++j) a += t[j] * sW2[j * DD + d];
    z2[d] = a;
    float rs = waveReduce(a);
    float rq = waveReduce(a * a);
    if (lane0) { atomicAdd(&ssum[d], rs); atomicAdd(&ssq[d], rq); }
  }
  pack9(X8, X1, n, z2);
  __syncthreads();
  int copy = ((int)blockIdx.x & 63) * 64;
  if (tid < DD) {
    atomicAdd(&stats[copy + NSUM2 + tid], ssum[tid]);
    atomicAdd(&stats[copy + NSQ2 + tid], ssq[tid]);
  }
}

// h_new = bn2(z2)[relu] + h_in; vn add + packed h + mirrors; last: spread out-sums
__global__ void __launch_bounds__(256)
k_partC(const uv4* __restrict__ X8, const unsigned short* __restrict__ X1,
        uv4* __restrict__ hb8, unsigned short* __restrict__ hb1,
        uint2* __restrict__ hmA, unsigned char* __restrict__ hmB,
        float* __restrict__ stats, const float* __restrict__ g2,
        const float* __restrict__ be2, const int* __restrict__ batch,
        const float* __restrict__ vn_next, float* __restrict__ vnsum_out,
        int do_relu) {
  __shared__ float sc[DD], sh[DD], ssum[DD];
  int tid = threadIdx.x;
  if (tid < DD) {
    float s = 0.f, q = 0.f;
#pragma unroll
    for (int c = 0; c < 64; ++c) {
      s += stats[c * 64 + NSUM2 + tid];
      q += stats[c * 64 + NSQ2 + tid];
    }
    float mean = s * (1.0f / NN);
    float var = q * (1.0f / NN) - mean * mean;
    float sg = g2[tid] * rsqrtf(var + BN_EPS);
    sc[tid] = sg;
    sh[tid] = be2[tid] - mean * sg;
    ssum[tid] = 0.f;
  }
  __syncthreads();
  size_t n = (size_t)blockIdx.x * 256 + tid;
  float zv[DD];
  unpack9(X8, X1, n, zv);
  float hi[DD];
  unpack9(hb8, hb1, n, hi);
  float hv[DD];
#pragma unroll
  for (int d = 0; d < DD; ++d) {
    float z = zv[d] * sc[d] + sh[d];
    if (do_relu) z = z > 0.f ? z : 0.f;
    hv[d] = z + hi[d];
  }
  if (vn_next != nullptr) {
    int g = batch[n];
#pragma unroll
    for (int d = 0; d < DD; ++d) hv[d] += vn_next[(size_t)g * DD + d];
    pack9(hb8, hb1, n, hv);
    writeMirror(hmA, hmB, n, hv);
    if (vnsum_out != nullptr) {
      int lane = tid & 63;
      float s[DD];
#pragma unroll
      for (int d = 0; d < DD; ++d) s[d] = hv[d];
#pragma unroll
      for (int st = 1; st < 64; st <<= 1) {
        int gu = __shfl_up(g, st, 64);
        bool ok = (lane >= st) && (gu == g);
#pragma unroll
        for (int d = 0; d < DD; ++d) {
          float vu = __shfl_up(s[d], st, 64);
          if (ok) s[d] += vu;
        }
      }
      int gn = __shfl_down(g, 1, 64);
      if ((lane == 63) || (gn != g)) {
#pragma unroll
        for (int d = 0; d < DD; ++d) atomicAdd(&vnsum_out[(size_t)g * DD + d], s[d]);
      }
    }
  } else {
    int lane0 = ((tid & 63) == 0);
#pragma unroll
    for (int d = 0; d < DD; ++d) {
      float r = waveReduce(hv[d]);
      if (lane0) atomicAdd(&ssum[d], r);
    }
    __syncthreads();
    int copy = ((int)blockIdx.x & 63) * 64;
    if (tid < DD) atomicAdd(&stats[copy + OUTS + tid], ssum[tid]);
  }
}

// reduce spread out-sums -> d_out
__global__ void k_out(const float* __restrict__ stats, float* __restrict__ out) {
  int tid = threadIdx.x;
  if (tid < DD) {
    float s = 0.f;
#pragma unroll
    for (int c = 0; c < 64; ++c) s += stats[c * 64 + OUTS + tid];
    out[tid] = s;
  }
}

// ---------------- virtual-node MLP (3 kernels, proven round-10 form) ----------------

__global__ void k_vnA(const float* __restrict__ vnsum, const float* __restrict__ vn,
                      float* __restrict__ vt1, const float* __restrict__ W1l,
                      const float* __restrict__ b1l, float* __restrict__ stats) {
  __shared__ float sW[DD * HH], sb[HH], ssum[HH], ssq[HH];
  int tid = threadIdx.x;
  for (int i = tid; i < DD * HH; i += 256) sW[i] = W1l[i];
  if (tid < HH) { sb[tid] = b1l[tid]; ssum[tid] = 0.f; ssq[tid] = 0.f; }
  __syncthreads();
  size_t g = (size_t)blockIdx.x * 256 + tid;
  float r[DD];
#pragma unroll
  for (int d = 0; d < DD; ++d) r[d] = vnsum[g * DD + d] + vn[g * DD + d];
  int lane0 = ((tid & 63) == 0);
#pragma unroll
  for (int j = 0; j < HH; ++j) {
    float a = sb[j];
#pragma unroll
    for (int d = 0; d < DD; ++d) a += r[d] * sW[d * HH + j];
    vt1[g * HH + j] = a;
    float rs = waveReduce(a);
    float rq = waveReduce(a * a);
    if (lane0) { atomicAdd(&ssum[j], rs); atomicAdd(&ssq[j], rq); }
  }
  __syncthreads();
  if (tid < HH) {
    atomicAdd(&stats[VSUM1 + tid], ssum[tid]);
    atomicAdd(&stats[VSQ1 + tid], ssq[tid]);
  }
}

__global__ void k_vnB(const float* __restrict__ vt1, float* __restrict__ vt2,
                      const float* __restrict__ W2l, const float* __restrict__ b2l,
                      const float* __restrict__ g1, const float* __restrict__ be1,
                      float* __restrict__ stats) {
  __shared__ float sW2[HH * DD], sb2[DD], sc1[HH], sh1[HH], ssum[DD], ssq[DD];
  int tid = threadIdx.x;
  for (int i = tid; i < HH * DD; i += 256) sW2[i] = W2l[i];
  if (tid < HH) {
    float mean = stats[VSUM1 + tid] * (1.0f / NG);
    float var = stats[VSQ1 + tid] * (1.0f / NG) - mean * mean;
    float sc = g1[tid] * rsqrtf(var + BN_EPS);
    sc1[tid] = sc;
    sh1[tid] = be1[tid] - mean * sc;
  }
  if (tid < DD) { sb2[tid] = b2l[tid]; ssum[tid] = 0.f; ssq[tid] = 0.f; }
  __syncthreads();
  size_t g = (size_t)blockIdx.x * 256 + tid;
  float t[HH];
#pragma unroll
  for (int j = 0; j < HH; ++j) {
    float a = vt1[g * HH + j] * sc1[j] + sh1[j];
    t[j] = a > 0.f ? a : 0.f;
  }
  int lane0 = ((tid & 63) == 0);
#pragma unroll
  for (int d = 0; d < DD; ++d) {
    float a = sb2[d];
#pragma unroll
    for (int j = 0; j < HH; ++j) a += t[j] * sW2[j * DD + d];
    vt2[g * DD + d] = a;
    float rs = waveReduce(a);
    float rq = waveReduce(a * a);
    if (lane0) { atomicAdd(&ssum[d], rs); atomicAdd(&ssq[d], rq); }
  }
  __syncthreads();
  if (tid < DD) {
    atomicAdd(&stats[VSUM2 + tid], ssum[tid]);
    atomicAdd(&stats[VSQ2 + tid], ssq[tid]);
  }
}

__global__ void k_vnC(const float* __restrict__ vt2, float* __restrict__ vn,
                      const float* __restrict__ g2, const float* __restrict__ be2,
                      const float* __restrict__ stats) {
  __shared__ float sc[DD], sh[DD];
  int tid = threadIdx.x;
  if (tid < DD) {
    float mean = stats[VSUM2 + tid] * (1.0f / NG);
    float var = stats[VSQ2 + tid] * (1.0f / NG) - mean * mean;
    float s = g2[tid] * rsqrtf(var + BN_EPS);
    sc[tid] = s;
    sh[tid] = be2[tid] - mean * s;
  }
  __syncthreads();
  size_t g = (size_t)blockIdx.x * 256 + tid;
#pragma unroll
  for (int d = 0; d < DD; ++d) {
    float v = vt2[g * DD + d] * sc[d] + sh[d];
    v = v > 0.f ? v : 0.f;
    vn[g * DD + d] += v;
  }
}

extern "C" void kernel_launch(void* const* d_in, const int* in_sizes, int n_in,
                              void* d_out, int out_size, void* d_ws, size_t ws_size,
                              hipStream_t stream) {
  const float* atom_emb = (const float*)d_in[0];
  const float* bond_emb = (const float*)d_in[1];
  const float* eps_gin  = (const float*)d_in[2];
  const float* W1   = (const float*)d_in[3];
  const float* b1   = (const float*)d_in[4];
  const float* bn1_g = (const float*)d_in[5];
  const float* bn1_b = (const float*)d_in[6];
  const float* W2   = (const float*)d_in[7];
  const float* b2   = (const float*)d_in[8];
  const float* bno_g = (const float*)d_in[9];
  const float* bno_b = (const float*)d_in[10];
  const float* vnW1 = (const float*)d_in[11];
  const float* vnb1 = (const float*)d_in[12];
  const float* vnbn1_g = (const float*)d_in[13];
  const float* vnbn1_b = (const float*)d_in[14];
  const float* vnW2 = (const float*)d_in[15];
  const float* vnb2 = (const float*)d_in[16];
  const float* vnbn2_g = (const float*)d_in[17];
  const float* vnbn2_b = (const float*)d_in[18];
  const int* x          = (const int*)d_in[19];
  const int* edge_index = (const int*)d_in[20];
  const int* edge_attr  = (const int*)d_in[21];
  const int* batch      = (const int*)d_in[22];
  float* out = (float*)d_out;

  // workspace layout — ~115 MB.
  // Region 0: union of transient coarse (NE uint2, 67.1 MB) + cnt_pad + blkcnt
  // with persistent hb8/hb1/X8/X1 packed bf16 node streams (37.75 MB, live
  // from k_atom which runs after all transient users are done).
  char* base = (char*)d_ws;
  uv4* hb8 = (uv4*)base;                                 // NN uint4
  unsigned short* hb1 = (unsigned short*)(hb8 + (size_t)NN);
  uv4* X8 = (uv4*)(hb1 + (size_t)NN);                    // NN uint4
  unsigned short* X1 = (unsigned short*)(X8 + (size_t)NN);
  uint2* coarse = (uint2*)base;                          // NE uint2 (transient)
  int* cnt_pad  = (int*)(coarse + (size_t)NE);           // NB*16 (transient)
  int* blkcnt   = cnt_pad + (size_t)NB * 16;             // NGRP*P1B (transient)
  char* pers = (char*)(blkcnt + (size_t)NGRP * P1B);
  uint2* hmA   = (uint2*)pers;                           // NN uint2 (8 MB)
  unsigned char* hmB = (unsigned char*)(hmA + (size_t)NN);  // NN bytes (1 MB)
  unsigned* binned = (unsigned*)(hmB + (size_t)NN);      // NE u32 (33.5 MB)
  float* vn    = (float*)(binned + (size_t)NE);          // NG*DD
  float* vnsum = vn + (size_t)NG * DD;                   // NG*DD (vt2 overlays)
  float* vt2   = vnsum;
  float* vt1   = vnsum + (size_t)NG * DD;                // NG*HH
  float* stats = vt1 + (size_t)NG * HH;                  // 3*STATS_FLOATS
  int* bucket_base   = (int*)(stats + 3 * STATS_FLOATS); // NB+1
  int* bucket_cursor = bucket_base + NB + 1;             // NB
  int* row_ptr       = bucket_cursor + NB;               // NN+1 (4 MB)
  unsigned* rpo      = (unsigned*)(row_ptr + NN + 1);    // NN u32 (4 MB)

  // ---- one-time binning (deterministic two-pass) ----
  (void)hipMemsetAsync(cnt_pad, 0, (size_t)NB * 16 * sizeof(int), stream);
  k_counthist<<<P1B, 1024, 0, stream>>>(edge_index, cnt_pad, blkcnt);
  k_scan<<<1, 256, 0, stream>>>(cnt_pad, bucket_base, bucket_cursor);
  k_scanG<<<NGRP, 256, 0, stream>>>(blkcnt, bucket_base);
  k_p1<<<P1B, 1024, 0, stream>>>(edge_index, edge_attr, blkcnt, coarse);
  k_p2<<<NGRP * P2SUB, 256, 0, stream>>>(coarse, bucket_base, bucket_cursor, binned);
  k_p3<<<NB, 256, 0, stream>>>(binned, bucket_base, row_ptr, rpo);

  // one upfront zero of vn + vnsum + vt1 + all 3 per-layer stats copies
  (void)hipMemsetAsync(vn, 0,
      ((size_t)2 * NG * DD + (size_t)NG * HH + 3 * STATS_FLOATS) * sizeof(float),
      stream);
  k_atom<<<NN / 256, 256, 0, stream>>>(atom_emb, x, batch, hb8, hb1, hmA, hmB, vnsum);

  for (int l = 0; l < 3; ++l) {
    int has_vn = (l < 2);
    float* stl = stats + (size_t)l * STATS_FLOATS;
    if (has_vn) {
      k_vnA<<<NG / 256, 256, 0, stream>>>(vnsum, vn, vt1, vnW1 + (size_t)l * DD * HH,
                                          vnb1 + (size_t)l * HH, stl);
      k_vnB<<<NG / 256, 256, 0, stream>>>(vt1, vt2, vnW2 + (size_t)l * HH * DD,
                                          vnb2 + (size_t)l * DD,
                                          vnbn1_g + (size_t)l * HH, vnbn1_b + (size_t)l * HH,
                                          stl);
      k_vnC<<<NG / 256, 256, 0, stream>>>(vt2, vn, vnbn2_g + (size_t)l * DD,
                                          vnbn2_b + (size_t)l * DD, stl);
    }
    k_edgeA<<<NB, 256, 0, stream>>>(hb8, hb1, hmA, hmB, binned, row_ptr, rpo,
                                    bond_emb + (size_t)l * 3 * 6 * DD,
                                    W1 + (size_t)l * DD * HH, b1 + (size_t)l * HH,
                                    eps_gin + l, X8, X1, stl);
    k_partB<<<NN / 256, 256, 0, stream>>>(X8, X1, W1 + (size_t)l * DD * HH,
                                          b1 + (size_t)l * HH,
                                          bn1_g + (size_t)l * HH, bn1_b + (size_t)l * HH,
                                          W2 + (size_t)l * HH * DD, b2 + (size_t)l * DD,
                                          stl);
    if (l == 0)
      (void)hipMemsetAsync(vnsum, 0, (size_t)NG * DD * sizeof(float), stream);
    k_partC<<<NN / 256, 256, 0, stream>>>(X8, X1, hb8, hb1, hmA, hmB, stl,
                                          bno_g + (size_t)l * DD, bno_b + (size_t)l * DD,
                                          batch,
                                          has_vn ? vn : nullptr,
                                          (l == 0) ? vnsum : nullptr,
                                          has_vn ? 1 : 0);
  }
  k_out<<<1, 64, 0, stream>>>(stats + 2 * STATS_FLOATS, out);
}